// Round 9
// baseline (401.345 us; speedup 1.0000x reference)
//
#include <hip/hip_runtime.h>
#include <hip/hip_bf16.h>

typedef __hip_bfloat16 bf16;
typedef float f32x4 __attribute__((ext_vector_type(4)));
typedef short bf16x8s __attribute__((ext_vector_type(8)));

constexpr int N_HE = 50000;
constexpr int M_PAD = 50048;           // 391 * 128
constexpr int E_EDGES = 1200000;
constexpr int IN_F = 200;
constexpr int KP_HE = 224;             // 200 padded to x32
constexpr int HE_DIM = 512;
constexpr int E_DIM = 128;
constexpr int Q_DIM = 64;
constexpr float SCALE = 0.125f;        // 1/sqrt(64)
constexpr int N_NODES = 167 + 881 + 441; // 1489
constexpr int R_STRIDE = 216;          // 3 x 72 (64 r + 1 c + 7 pad)
constexpr int T_STRIDE = 192;          // 3 x 64
constexpr int LDSD = 40;               // LDS row stride (bf16) for GEMM staging
constexpr int NBIN = 98;               // ceil(50000/512) bins per group
constexpr int BIN_SHIFT = 9;           // 512 hyperedges per bin
constexpr int ECHUNK = 4096;           // edges per bin_scatter block
constexpr int BINCAP = 13056;          // mean 12288 + 7 sigma, clamp-guarded

struct GroupPtrs {
    const float* feat[3];
    const float* wa[3];
    const float* ba[3];
};
struct EdgeIdx { const int* p[3]; };

__device__ __forceinline__ void split2(float v, bf16& h, bf16& l)
{
    bf16 hb = __float2bfloat16(v);
    h = hb;
    l = __float2bfloat16(v - __bfloat162float(hb));
}

// ---------------- split he_feat -> [M_PAD][224] bf16 hi/lo ----------------
__global__ __launch_bounds__(256) void split_hefeat_kernel(
    const float* __restrict__ x, bf16* __restrict__ hi, bf16* __restrict__ lo)
{
    int idx = blockIdx.x * 256 + threadIdx.x; // over N_HE*224 exactly
    int row = idx / KP_HE, k = idx - row * KP_HE;
    float v = (k < IN_F) ? x[(size_t)row * IN_F + k] : 0.f;
    bf16 h, l;
    split2(v, h, l);
    hi[idx] = h; lo[idx] = l;
}

// ---------------- compose W12 -> W12t hi/lo [128][224]; bias -> b12 ----------------
__global__ __launch_bounds__(256) void compose_w12_kernel(
    const float* __restrict__ w1w, const float* __restrict__ w1b,
    const float* __restrict__ w2w, const float* __restrict__ w2b,
    bf16* __restrict__ W12t_hi, bf16* __restrict__ W12t_lo, float* __restrict__ b12)
{
    int row = blockIdx.x; // 0..200
    int col = threadIdx.x & 127, ks = threadIdx.x >> 7;
    const float* a = (row < IN_F) ? (w1w + (size_t)row * HE_DIM) : w1b;
    float s = 0.f;
#pragma unroll 4
    for (int k = ks; k < HE_DIM; k += 2)
        s = fmaf(a[k], w2w[k * E_DIM + col], s);
    __shared__ float red[2][128];
    red[ks][col] = s;
    __syncthreads();
    if (ks == 0) {
        float v = red[0][col] + red[1][col];
        if (row < IN_F) {
            bf16 h, l; split2(v, h, l);
            W12t_hi[col * KP_HE + row] = h;
            W12t_lo[col * KP_HE + row] = l;
        } else b12[col] = v + w2b[col];
    }
}

// ---------------- Bt_kv hi/lo [256][128] ----------------
__global__ __launch_bounds__(256) void prep_bkv_kernel(
    const float* __restrict__ w6m, const float* __restrict__ b6m,
    const float* __restrict__ w6p, const float* __restrict__ b6p,
    const float* __restrict__ w6e, const float* __restrict__ b6e,
    bf16* __restrict__ Bt_hi, bf16* __restrict__ Bt_lo)
{
    int k = blockIdx.x;   // 0..127
    int c = threadIdx.x;  // 0..255
    if (c >= R_STRIDE) return;
    int g = c / 72, j = c - g * 72;
    const float* w6 = (g == 0) ? w6m : (g == 1) ? w6p : w6e;
    const float* b6 = (g == 0) ? b6m : (g == 1) ? b6p : b6e;
    float v = 0.f;
    if (j < 64) v = w6[j * E_DIM + k];
    else if (j == 64) v = b6[k];
    bf16 h, l; split2(v, h, l);
    Bt_hi[c * E_DIM + k] = h;
    Bt_lo[c * E_DIM + k] = l;
}

// ---------------- W_comp^T hi/lo [256][192]; b_comp f32[256] ----------------
__global__ __launch_bounds__(256) void prep_wcomp_kernel(
    const float* __restrict__ w7m, const float* __restrict__ b7m,
    const float* __restrict__ w7p, const float* __restrict__ b7p,
    const float* __restrict__ w7e, const float* __restrict__ b7e,
    const float* __restrict__ mlp1w, const float* __restrict__ mlp1b,
    bf16* __restrict__ Wct_hi, bf16* __restrict__ Wct_lo, float* __restrict__ bc)
{
    int row = blockIdx.x; // 0..192 (192 = bias row)
    int n = threadIdx.x;  // 0..255
    if (row < 192) {
        int g = row >> 6, i = row & 63;
        const float* w7 = (g == 0) ? w7m : (g == 1) ? w7p : w7e;
        float s = 0.f;
#pragma unroll 4
        for (int k = 0; k < 128; ++k)
            s = fmaf(w7[i * 128 + k], mlp1w[(size_t)(g * 128 + k) * 256 + n], s);
        bf16 h, l; split2(s, h, l);
        Wct_hi[n * T_STRIDE + row] = h;
        Wct_lo[n * T_STRIDE + row] = l;
    } else {
        const float* b7s[3] = {b7m, b7p, b7e};
        float s = mlp1b[n];
        for (int g = 0; g < 3; ++g)
#pragma unroll 4
            for (int k = 0; k < 128; ++k)
                s = fmaf(b7s[g][k], mlp1w[(size_t)(g * 128 + k) * 256 + n], s);
        bc[n] = s;
    }
}

// ---------------- mlp2w^T hi/lo [128][256] ----------------
__global__ __launch_bounds__(256) void prep_m2t_kernel(
    const float* __restrict__ w, bf16* __restrict__ Wt_hi, bf16* __restrict__ Wt_lo)
{
    int n = blockIdx.x;   // 0..127
    int k = threadIdx.x;  // 0..255
    float v = w[(size_t)k * 128 + n];
    bf16 h, l; split2(v, h, l);
    Wt_hi[n * 256 + k] = h;
    Wt_lo[n * 256 + k] = l;
}

// ---------------- fused node q projection ----------------
__global__ __launch_bounds__(256) void node_q_fused_kernel(GroupPtrs P, float* __restrict__ qt)
{
    int b = blockIdx.x; // 0..1488
    int g = (b < 167) ? 0 : (b < 1048 ? 1 : 2);
    int row = b - (g == 0 ? 0 : (g == 1 ? 167 : 1048));
    int Dt = (g == 0) ? 167 : (g == 1 ? 881 : 441);
    const float* feat = P.feat[g] + (size_t)row * Dt;
    const float* w5 = P.wa[g];
    int col = threadIdx.x & 63, ks = threadIdx.x >> 6;
    float s = 0.f;
#pragma unroll 4
    for (int k = ks; k < Dt; k += 4)
        s = fmaf(feat[k], w5[k * Q_DIM + col], s);
    __shared__ float red[4][64];
    red[ks][col] = s;
    __syncthreads();
    if (ks == 0) {
        qt[(size_t)b * Q_DIM + col] =
            red[0][col] + red[1][col] + red[2][col] + red[3][col] + P.ba[g][col];
    }
}

// ---------------- split-precision bf16 MFMA GEMM ----------------
template <bool BIAS, bool RELU, bool SPLIT_OUT>
__global__ __launch_bounds__(256) void mfma_gemm_kernel(
    const bf16* __restrict__ Ahg, const bf16* __restrict__ Alg, int Kp,
    const bf16* __restrict__ Bthg, const bf16* __restrict__ Btlg,
    const float* __restrict__ bias,
    float* __restrict__ Cf, bf16* __restrict__ Ch, bf16* __restrict__ Cl,
    int M, int N, int ldc)
{
    __shared__ bf16 Ah[128 * LDSD], Al[128 * LDSD], Bh[64 * LDSD], Bl[64 * LDSD];
    const int tid = threadIdx.x;
    const int bm = blockIdx.x * 128, bn = blockIdx.y * 64;
    const int lane = tid & 63, w = tid >> 6;
    const int kgrp = lane >> 4, lr = lane & 15;
    const int arow = tid >> 1, ahalf = (tid & 1) * 16;
    const int brow = tid >> 2, bq = (tid & 3) * 8;
    f32x4 acc[2][4] = {};

    for (int k0 = 0; k0 < Kp; k0 += 32) {
        {
            const size_t abase = (size_t)(bm + arow) * Kp + k0 + ahalf;
            uint4 v0 = *(const uint4*)(Ahg + abase);
            uint4 v1 = *(const uint4*)(Ahg + abase + 8);
            uint4 u0 = *(const uint4*)(Alg + abase);
            uint4 u1 = *(const uint4*)(Alg + abase + 8);
            *(uint4*)&Ah[arow * LDSD + ahalf] = v0;
            *(uint4*)&Ah[arow * LDSD + ahalf + 8] = v1;
            *(uint4*)&Al[arow * LDSD + ahalf] = u0;
            *(uint4*)&Al[arow * LDSD + ahalf + 8] = u1;
            const size_t bbase = (size_t)(bn + brow) * Kp + k0 + bq;
            uint4 w0 = *(const uint4*)(Bthg + bbase);
            uint4 w1 = *(const uint4*)(Btlg + bbase);
            *(uint4*)&Bh[brow * LDSD + bq] = w0;
            *(uint4*)&Bl[brow * LDSD + bq] = w1;
        }
        __syncthreads();
        bf16x8s afh[2], afl[2], bfh[4], bfl[4];
#pragma unroll
        for (int mi = 0; mi < 2; ++mi) {
            int r = w * 32 + mi * 16 + lr;
            afh[mi] = *(const bf16x8s*)&Ah[r * LDSD + kgrp * 8];
            afl[mi] = *(const bf16x8s*)&Al[r * LDSD + kgrp * 8];
        }
#pragma unroll
        for (int ni = 0; ni < 4; ++ni) {
            int r = ni * 16 + lr;
            bfh[ni] = *(const bf16x8s*)&Bh[r * LDSD + kgrp * 8];
            bfl[ni] = *(const bf16x8s*)&Bl[r * LDSD + kgrp * 8];
        }
#pragma unroll
        for (int mi = 0; mi < 2; ++mi)
#pragma unroll
            for (int ni = 0; ni < 4; ++ni) {
                acc[mi][ni] = __builtin_amdgcn_mfma_f32_16x16x32_bf16(afh[mi], bfh[ni], acc[mi][ni], 0, 0, 0);
                acc[mi][ni] = __builtin_amdgcn_mfma_f32_16x16x32_bf16(afl[mi], bfh[ni], acc[mi][ni], 0, 0, 0);
                acc[mi][ni] = __builtin_amdgcn_mfma_f32_16x16x32_bf16(afh[mi], bfl[ni], acc[mi][ni], 0, 0, 0);
            }
        __syncthreads();
    }

#pragma unroll
    for (int mi = 0; mi < 2; ++mi) {
#pragma unroll
        for (int ni = 0; ni < 4; ++ni) {
            int col = bn + ni * 16 + lr;
            float bv = 0.f;
            if (BIAS) bv = (col < N) ? bias[col] : 0.f;
            int row0 = bm + w * 32 + mi * 16 + kgrp * 4;
#pragma unroll
            for (int r = 0; r < 4; ++r) {
                float v = acc[mi][ni][r] + bv;
                if (RELU) v = fmaxf(v, 0.f);
                int row = row0 + r;
                if (SPLIT_OUT) {
                    bf16 h, l; split2(v, h, l);
                    Ch[(size_t)row * ldc + col] = h;
                    Cl[(size_t)row * ldc + col] = l;
                } else {
                    if (row < M && col < N) Cf[(size_t)row * ldc + col] = v;
                }
            }
        }
    }
}

// ================= binned CSR build (fixed-capacity slots; no global scan) =================
// bin edges: per-wave LDS hist, LDS sort by bin, reserve fixed-slot space, coalesced copy-out
__global__ __launch_bounds__(256) void bin_scatter_kernel(
    EdgeIdx S, EdgeIdx D, int* __restrict__ bincursor, unsigned* __restrict__ binbuf)
{
    int g = blockIdx.y;
    const int* src = S.p[g];
    const int* dst = D.p[g];
    __shared__ unsigned stage[ECHUNK];
    __shared__ int hist4[4][NBIN];
    __shared__ int hist[NBIN], off[NBIN], cur[NBIN], gbase[NBIN];
    int tid = threadIdx.x, lane = tid & 63, w = tid >> 6;
    for (int b = tid; b < 4 * NBIN; b += 256) (&hist4[0][0])[b] = 0;
    __syncthreads();

    int base = blockIdx.x * ECHUNK;
    int s[ECHUNK / 256], d[ECHUNK / 256];
#pragma unroll
    for (int k = 0; k < ECHUNK / 256; ++k) {
        int i = base + k * 256 + tid;
        if (i < E_EDGES) {
            s[k] = src[i];
            d[k] = dst[i];
            atomicAdd(&hist4[w][s[k] >> BIN_SHIFT], 1);
        } else s[k] = -1;
    }
    __syncthreads();
    // merge 4 wave-hists + scan on wave 0
    if (w == 0) {
        int i1 = 64 + lane;
        int v0 = 0, v1 = 0;
        if (lane < NBIN) v0 = hist4[0][lane] + hist4[1][lane] + hist4[2][lane] + hist4[3][lane];
        if (i1 < NBIN) v1 = hist4[0][i1] + hist4[1][i1] + hist4[2][i1] + hist4[3][i1];
        int x0 = v0, x1 = v1;
#pragma unroll
        for (int o = 1; o < 64; o <<= 1) {
            int t0 = __shfl_up(x0, o, 64);
            int t1 = __shfl_up(x1, o, 64);
            if (lane >= o) { x0 += t0; x1 += t1; }
        }
        int tot0 = __shfl(x0, 63, 64);
        if (lane < NBIN) { hist[lane] = v0; off[lane] = x0 - v0; cur[lane] = x0 - v0; }
        if (i1 < NBIN) { hist[i1] = v1; off[i1] = tot0 + x1 - v1; cur[i1] = tot0 + x1 - v1; }
    }
    __syncthreads();
    if (tid < NBIN) gbase[tid] = hist[tid] ? atomicAdd(&bincursor[g * NBIN + tid], hist[tid]) : 0;
    __syncthreads();
#pragma unroll
    for (int k = 0; k < ECHUNK / 256; ++k) {
        if (s[k] >= 0) {
            int bin = s[k] >> BIN_SHIFT;
            int pos = atomicAdd(&cur[bin], 1);
            stage[pos] = ((unsigned)(s[k] & 511) << 10) | (unsigned)d[k];
        }
    }
    __syncthreads();
    // copy out into fixed bin slots: wave w handles bins w, w+4, ...
    size_t gslot = (size_t)g * NBIN * BINCAP;
    for (int b = w; b < NBIN; b += 4) {
        int len = hist[b];
        if (!len) continue;
        int gb = gbase[b];
        int avail = BINCAP - gb;                 // overflow clamp (7-sigma margin)
        if (avail <= 0) continue;
        if (len > avail) len = avail;
        int lo = off[b];
        size_t obase = gslot + (size_t)b * BINCAP + gb;
        for (int j = lane; j < len; j += 64)
            binbuf[obase + j] = stage[lo + j];
    }
}

// per-bin CSR: LDS 512-hist + scan -> rows2 (start,end); localized scatter -> ebuf slot
__global__ __launch_bounds__(256) void bin_csr_kernel(
    const unsigned* __restrict__ binbuf, const int* __restrict__ bincursor,
    int2* __restrict__ rows2_all, int* __restrict__ ebuf)
{
    int b = blockIdx.x, g = blockIdx.y;
    int cnt = min(bincursor[g * NBIN + b], BINCAP);
    size_t sbase = ((size_t)g * NBIN + b) * BINCAP;
    int h0 = b << BIN_SHIFT;
    int hN = min(512, N_HE - h0);
    int ebase_rel = b * BINCAP; // group-relative base of this bin's ebuf slot
    int2* rows2 = rows2_all + g * N_HE;
    __shared__ int hist[512], cur[512], cs[8];
    int tid = threadIdx.x, lane = tid & 63, w = tid >> 6;
    hist[tid] = 0; hist[tid + 256] = 0;
    __syncthreads();
    for (int i = tid; i < cnt; i += 256)
        atomicAdd(&hist[binbuf[sbase + i] >> 10], 1);
    __syncthreads();
    // scan 512 = 8 chunks of 64; wave w owns chunks 2w, 2w+1
#pragma unroll
    for (int c2 = 0; c2 < 2; ++c2) {
        int c = w * 2 + c2, idx = c * 64 + lane;
        int v = hist[idx], x = v;
#pragma unroll
        for (int o = 1; o < 64; o <<= 1) {
            int t = __shfl_up(x, o, 64);
            if (lane >= o) x += t;
        }
        cur[idx] = x - v;
        if (lane == 63) cs[c] = x;
    }
    __syncthreads();
    if (tid == 0) {
        int run = 0;
#pragma unroll
        for (int c = 0; c < 8; ++c) { int t = cs[c]; cs[c] = run; run += t; }
    }
    __syncthreads();
#pragma unroll
    for (int c2 = 0; c2 < 2; ++c2) {
        int c = w * 2 + c2, idx = c * 64 + lane;
        int e = cur[idx] + cs[c];
        cur[idx] = e;
        if (idx < hN) rows2[h0 + idx] = make_int2(ebase_rel + e, ebase_rel + e + hist[idx]);
    }
    __syncthreads();
    for (int i = tid; i < cnt; i += 256) {
        unsigned p = binbuf[sbase + i];
        int pos = atomicAdd(&cur[p >> 10], 1);
        ebuf[sbase + pos] = (int)(p & 1023u);
    }
}

// ---------------- attention on reduced 64-dim states (4-edge unroll) ----------------
__global__ __launch_bounds__(256) void attn_kernel(
    const float* __restrict__ R,        // [N_HE][216]
    const float* __restrict__ q_t,      // [1489][64]
    const int2* __restrict__ rows2_all, // [3][N_HE] (start,end) group-relative
    const int* __restrict__ ebuf_all,   // [3][NBIN*BINCAP]
    bf16* __restrict__ T_hi, bf16* __restrict__ T_lo) // [M_PAD][192]
{
    int wid = blockIdx.x * 4 + (threadIdx.x >> 6);
    int lane = threadIdx.x & 63;
    int g = wid / N_HE;
    int h = wid - g * N_HE;
    const int toff_tab[3] = {0, 167, 1048};
    const float* qt = q_t + (size_t)toff_tab[g] * Q_DIM;
    const int* ebuf = ebuf_all + (size_t)g * NBIN * BINCAP;
    int2 se = rows2_all[g * N_HE + h];
    int start = se.x, end = se.y;

    int sub = lane >> 4, sl = lane & 15;
    const float* Rrow = R + (size_t)h * R_STRIDE + g * 72;
    float4 r4 = *reinterpret_cast<const float4*>(Rrow + sl * 4);
    float ch = Rrow[64];

    float m = -INFINITY, denom = 0.f;
    float acc0 = 0.f, acc1 = 0.f, acc2 = 0.f, acc3 = 0.f;

    for (int i0 = start + sub * 4; i0 < end; i0 += 16) {
        int n_ok = end - i0; // >=1
        int d0 = ebuf[i0];
        int d1 = ebuf[n_ok > 1 ? i0 + 1 : i0];
        int d2 = ebuf[n_ok > 2 ? i0 + 2 : i0];
        int d3 = ebuf[n_ok > 3 ? i0 + 3 : i0];
        float4 t0 = *reinterpret_cast<const float4*>(qt + (size_t)d0 * Q_DIM + sl * 4);
        float4 t1 = *reinterpret_cast<const float4*>(qt + (size_t)d1 * Q_DIM + sl * 4);
        float4 t2 = *reinterpret_cast<const float4*>(qt + (size_t)d2 * Q_DIM + sl * 4);
        float4 t3 = *reinterpret_cast<const float4*>(qt + (size_t)d3 * Q_DIM + sl * 4);
        float p0 = t0.x * r4.x; p0 = fmaf(t0.y, r4.y, p0); p0 = fmaf(t0.z, r4.z, p0); p0 = fmaf(t0.w, r4.w, p0);
        float p1 = t1.x * r4.x; p1 = fmaf(t1.y, r4.y, p1); p1 = fmaf(t1.z, r4.z, p1); p1 = fmaf(t1.w, r4.w, p1);
        float p2 = t2.x * r4.x; p2 = fmaf(t2.y, r4.y, p2); p2 = fmaf(t2.z, r4.z, p2); p2 = fmaf(t2.w, r4.w, p2);
        float p3 = t3.x * r4.x; p3 = fmaf(t3.y, r4.y, p3); p3 = fmaf(t3.z, r4.z, p3); p3 = fmaf(t3.w, r4.w, p3);
#pragma unroll
        for (int mask = 1; mask < 16; mask <<= 1) {
            p0 += __shfl_xor(p0, mask, 64);
            p1 += __shfl_xor(p1, mask, 64);
            p2 += __shfl_xor(p2, mask, 64);
            p3 += __shfl_xor(p3, mask, 64);
        }
        float s0 = (p0 + ch) * SCALE; s0 = s0 > 0.f ? s0 : 0.01f * s0;
        float s1 = (p1 + ch) * SCALE; s1 = s1 > 0.f ? s1 : 0.01f * s1;
        float s2 = (p2 + ch) * SCALE; s2 = s2 > 0.f ? s2 : 0.01f * s2;
        float s3 = (p3 + ch) * SCALE; s3 = s3 > 0.f ? s3 : 0.01f * s3;
        if (n_ok < 2) s1 = -INFINITY;
        if (n_ok < 3) s2 = -INFINITY;
        if (n_ok < 4) s3 = -INFINITY;
        float newm = fmaxf(fmaxf(fmaxf(s0, s1), fmaxf(s2, s3)), m);
        float sc = __expf(m - newm);
        float w0 = __expf(s0 - newm);
        float w1 = __expf(s1 - newm);
        float w2 = __expf(s2 - newm);
        float w3 = __expf(s3 - newm);
        denom = fmaf(denom, sc, (w0 + w1) + (w2 + w3));
        acc0 = fmaf(w0, t0.x, fmaf(w1, t1.x, fmaf(w2, t2.x, fmaf(w3, t3.x, acc0 * sc))));
        acc1 = fmaf(w0, t0.y, fmaf(w1, t1.y, fmaf(w2, t2.y, fmaf(w3, t3.y, acc1 * sc))));
        acc2 = fmaf(w0, t0.z, fmaf(w1, t1.z, fmaf(w2, t2.z, fmaf(w3, t3.z, acc2 * sc))));
        acc3 = fmaf(w0, t0.w, fmaf(w1, t1.w, fmaf(w2, t2.w, fmaf(w3, t3.w, acc3 * sc))));
        m = newm;
    }

    float om = fmaxf(m, __shfl_xor(m, 16, 64));
    om = fmaxf(om, __shfl_xor(om, 32, 64));
    float f = (denom > 0.f) ? __expf(m - om) : 0.f;
    float d = denom * f;
    d += __shfl_xor(d, 16, 64);
    d += __shfl_xor(d, 32, 64);
    float a0 = acc0 * f, a1 = acc1 * f, a2 = acc2 * f, a3 = acc3 * f;
    a0 += __shfl_xor(a0, 16, 64); a0 += __shfl_xor(a0, 32, 64);
    a1 += __shfl_xor(a1, 16, 64); a1 += __shfl_xor(a1, 32, 64);
    a2 += __shfl_xor(a2, 16, 64); a2 += __shfl_xor(a2, 32, 64);
    a3 += __shfl_xor(a3, 16, 64); a3 += __shfl_xor(a3, 32, 64);
    if (sub == 0) {
        float rden = 1.f / fmaxf(d, 1e-20f);
        float o[4] = {a0 * rden, a1 * rden, a2 * rden, a3 * rden};
        size_t bix = (size_t)h * T_STRIDE + g * 64 + sl * 4;
#pragma unroll
        for (int e = 0; e < 4; ++e) {
            bf16 hh, ll; split2(o[e], hh, ll);
            T_hi[bix + e] = hh;
            T_lo[bix + e] = ll;
        }
    }
}

// ---------------- launch ----------------
extern "C" void kernel_launch(void* const* d_in, const int* in_sizes, int n_in,
                              void* d_out, int out_size, void* d_ws, size_t ws_size,
                              hipStream_t stream)
{
    const float* he_feat = (const float*)d_in[0];
    const float* w1w = (const float*)d_in[4];
    const float* w1b = (const float*)d_in[5];
    const float* w2w = (const float*)d_in[6];
    const float* w2b = (const float*)d_in[7];
    const float* w6w_g[3] = {(const float*)d_in[18], (const float*)d_in[22], (const float*)d_in[26]};
    const float* w6b_g[3] = {(const float*)d_in[19], (const float*)d_in[23], (const float*)d_in[27]};
    const float* w7w_g[3] = {(const float*)d_in[20], (const float*)d_in[24], (const float*)d_in[28]};
    const float* w7b_g[3] = {(const float*)d_in[21], (const float*)d_in[25], (const float*)d_in[29]};
    const float* mlp1w = (const float*)d_in[30];
    const float* mlp1b = (const float*)d_in[31];
    const float* mlp2w = (const float*)d_in[32];
    const float* mlp2b = (const float*)d_in[33];
    float* out = (float*)d_out;

    GroupPtrs Pq;
    for (int g = 0; g < 3; ++g) {
        Pq.feat[g] = (const float*)d_in[1 + g];
        Pq.wa[g] = (const float*)d_in[12 + 2 * g];
        Pq.ba[g] = (const float*)d_in[13 + 2 * g];
    }
    EdgeIdx Esrc, Edst;
    for (int g = 0; g < 3; ++g) {
        Esrc.p[g] = (const int*)d_in[34 + 2 * g];
        Edst.p[g] = (const int*)d_in[35 + 2 * g];
    }

    char* base = (char*)d_ws;
    size_t off = 0;
    auto alloc = [&](size_t bytes) -> void* {
        void* r = (void*)(base + off);
        off = (off + bytes + 255) & ~(size_t)255;
        return r;
    };
    // ---- persistent small region (~2.2 MB) ----
    bf16* W12t_hi = (bf16*)alloc(128 * KP_HE * 2);  // memset block start
    bf16* W12t_lo = (bf16*)alloc(128 * KP_HE * 2);
    bf16* Btkv_hi = (bf16*)alloc(256 * E_DIM * 2);
    bf16* Btkv_lo = (bf16*)alloc(256 * E_DIM * 2);  // memset block end (245760 B)
    float* b12 = (float*)alloc(128 * 4);
    bf16* Wct_hi = (bf16*)alloc(256 * T_STRIDE * 2);
    bf16* Wct_lo = (bf16*)alloc(256 * T_STRIDE * 2);
    float* b_comp = (float*)alloc(256 * 4);
    bf16* Wm2t_hi = (bf16*)alloc(128 * 256 * 2);
    bf16* Wm2t_lo = (bf16*)alloc(128 * 256 * 2);
    float* q_t = (float*)alloc(N_NODES * Q_DIM * 4);
    int* bincursor = (int*)alloc(3 * NBIN * 4);
    int2* rows2 = (int2*)alloc((size_t)3 * N_HE * 8);
    // ---- big buffers with lifetime overlays (total ~124.8 MB) ----
    size_t T_start = off;
    bf16* T_hi = (bf16*)alloc((size_t)M_PAD * T_STRIDE * 2);   // [attn -> mlp1]
    bf16* T_lo = (bf16*)alloc((size_t)M_PAD * T_STRIDE * 2);
    size_t R_start = off;
    float* R = (float*)alloc((size_t)N_HE * R_STRIDE * 4);     // [R-gemm -> attn]
    int* ebuf = (int*)alloc((size_t)3 * NBIN * BINCAP * 4);    // [bin_csr -> attn]
    bf16* qhe_hi = (bf16*)alloc((size_t)M_PAD * E_DIM * 2);    // [q_he gemm -> R gemm]
    bf16* qhe_lo = (bf16*)alloc((size_t)M_PAD * E_DIM * 2);
    // overlays:
    bf16* he_hi = (bf16*)(base + T_start);                      // phase A only (spills into R head; R written later)
    bf16* he_lo = he_hi + (size_t)M_PAD * KP_HE;
    unsigned* binbuf = (unsigned*)qhe_hi;                       // CSR staging, dead before q_he gemm
    bf16* h1_hi = (bf16*)(base + R_start);                      // mlp1 -> mlp2
    bf16* h1_lo = h1_hi + (size_t)M_PAD * 256;

    hipMemsetAsync(bincursor, 0, 3 * NBIN * 4, stream);
    hipMemsetAsync(W12t_hi, 0, 245760, stream); // zero-pads W12t + Btkv (hi & lo)

    // ---- binned CSR build (2 kernels) ----
    {
        dim3 grid((E_EDGES + ECHUNK - 1) / ECHUNK, 3);
        bin_scatter_kernel<<<grid, 256, 0, stream>>>(Esrc, Edst, bincursor, binbuf);
        bin_csr_kernel<<<dim3(NBIN, 3), 256, 0, stream>>>(binbuf, bincursor, rows2, ebuf);
    }

    // ---- phase A: splits, weight prep, node q ----
    split_hefeat_kernel<<<(N_HE * KP_HE) / 256, 256, 0, stream>>>(he_feat, he_hi, he_lo);
    compose_w12_kernel<<<IN_F + 1, 256, 0, stream>>>(w1w, w1b, w2w, w2b, W12t_hi, W12t_lo, b12);
    prep_bkv_kernel<<<128, 256, 0, stream>>>(w6w_g[0], w6b_g[0], w6w_g[1], w6b_g[1],
                                             w6w_g[2], w6b_g[2], Btkv_hi, Btkv_lo);
    prep_wcomp_kernel<<<193, 256, 0, stream>>>(w7w_g[0], w7b_g[0], w7w_g[1], w7b_g[1],
                                               w7w_g[2], w7b_g[2], mlp1w, mlp1b, Wct_hi, Wct_lo, b_comp);
    prep_m2t_kernel<<<128, 256, 0, stream>>>(mlp2w, Wm2t_hi, Wm2t_lo);
    node_q_fused_kernel<<<N_NODES, 256, 0, stream>>>(Pq, q_t);

    const int MB = M_PAD / 128; // 391
    // q_he = he_feat @ W12 + b12 -> split [M_PAD][128]   (overwrites binbuf: dead)
    mfma_gemm_kernel<true, false, true><<<dim3(MB, 2), 256, 0, stream>>>(
        he_hi, he_lo, KP_HE, W12t_hi, W12t_lo, b12, nullptr, qhe_hi, qhe_lo, N_HE, E_DIM, E_DIM);
    // R = q_he @ B_kv -> f32 [N_HE][216]
    mfma_gemm_kernel<false, false, false><<<dim3(MB, 4), 256, 0, stream>>>(
        qhe_hi, qhe_lo, E_DIM, Btkv_hi, Btkv_lo, nullptr, R, nullptr, nullptr, N_HE, R_STRIDE, R_STRIDE);
    // attention -> T split [M_PAD][192]   (overwrites he: dead)
    attn_kernel<<<(3 * N_HE) / 4, 256, 0, stream>>>(R, q_t, rows2, ebuf, T_hi, T_lo);
    // h1 = relu(T @ W_comp + b_comp) -> split [M_PAD][256]   (overwrites R/ebuf: dead)
    mfma_gemm_kernel<true, true, true><<<dim3(MB, 4), 256, 0, stream>>>(
        T_hi, T_lo, T_STRIDE, Wct_hi, Wct_lo, b_comp, nullptr, h1_hi, h1_lo, N_HE, 256, 256);
    // out = relu(h1 @ mlp2w + mlp2b) -> f32 [N_HE][128]
    mfma_gemm_kernel<true, true, false><<<dim3(MB, 2), 256, 0, stream>>>(
        h1_hi, h1_lo, 256, Wm2t_hi, Wm2t_lo, mlp2b, out, nullptr, nullptr, N_HE, E_DIM, E_DIM);
}

// Round 10
// 311.586 us; speedup vs baseline: 1.2881x; 1.2881x over previous
//
#include <hip/hip_runtime.h>
#include <hip/hip_bf16.h>

typedef __hip_bfloat16 bf16;
typedef float f32x4 __attribute__((ext_vector_type(4)));
typedef short bf16x8s __attribute__((ext_vector_type(8)));
typedef unsigned short u16x8 __attribute__((ext_vector_type(8)));

constexpr int N_HE = 50000;
constexpr int M_PAD = 50048;           // 391 * 128
constexpr int E_EDGES = 1200000;
constexpr int IN_F = 200;
constexpr int KP_HE = 224;             // 200 padded to x32
constexpr int HE_DIM = 512;
constexpr int E_DIM = 128;
constexpr int Q_DIM = 64;
constexpr float SCALE = 0.125f;        // 1/sqrt(64)
constexpr int N_NODES = 1489;
constexpr int R_STRIDE = 216;          // 3 x 72 (64 r + 1 c + 7 pad)
constexpr int T_STRIDE = 192;          // 3 x 64
constexpr int LDSD = 40;               // LDS row stride (bf16) for GEMM staging
constexpr int NBIN = 98;               // ceil(50000/512) bins per group
constexpr int BIN_SHIFT = 9;           // 512 hyperedges per bin
constexpr int ECHUNK = 4096;           // edges per bin_scatter block
constexpr int BINCAP = 13056;          // mean 12288 + 7 sigma, clamp-guarded

struct EdgeIdx { const int* p[3]; };

__device__ __forceinline__ void split2(float v, bf16& h, bf16& l)
{
    bf16 hb = __float2bfloat16(v);
    h = hb;
    l = __float2bfloat16(v - __bfloat162float(hb));
}
__device__ __forceinline__ void split2u(float v, unsigned short& h, unsigned short& l)
{
    bf16 hb = __float2bfloat16(v);
    bf16 lb = __float2bfloat16(v - __bfloat162float(hb));
    h = *reinterpret_cast<unsigned short*>(&hb);
    l = *reinterpret_cast<unsigned short*>(&lb);
}

// ================= fused prep (5 former kernels, block-range dispatch) =================
struct PrepArgs {
    const float *w1w, *w1b, *w2w, *w2b;
    float *W12f, *b12;
    const float *w6[3], *b6[3];
    float *Bkvf;
    const float *w7[3], *b7[3];
    const float *mlp1w, *mlp1b;
    bf16 *Wct_hi, *Wct_lo;
    float *b_comp;
    const float *mlp2w;
    bf16 *Wm2t_hi, *Wm2t_lo;
    const float *feat[3], *w5[3], *b5[3];
    float *q_t;
};

__global__ __launch_bounds__(256) void prep_fused_kernel(PrepArgs P)
{
    __shared__ float sh[256];
    int bid = blockIdx.x, tid = threadIdx.x;
    if (bid < 201) {
        // W12f[200][128] = w1w @ w2w (f32); row 200 -> b12
        int row = bid;
        int col = tid & 127, ks = tid >> 7;
        const float* a = (row < IN_F) ? (P.w1w + (size_t)row * HE_DIM) : P.w1b;
        float s = 0.f;
#pragma unroll 4
        for (int k = ks; k < HE_DIM; k += 2)
            s = fmaf(a[k], P.w2w[k * E_DIM + col], s);
        sh[ks * 128 + col] = s;
        __syncthreads();
        if (ks == 0) {
            float v = sh[col] + sh[128 + col];
            if (row < IN_F) P.W12f[row * E_DIM + col] = v;
            else P.b12[col] = v + P.w2b[col];
        }
    } else if (bid < 329) {
        // Bkvf[128][216] f32: col c=g*72+j -> w6_g^T / b6_g / 0
        int k = bid - 201;
        int c = tid;
        if (c < R_STRIDE) {
            int g = c / 72, j = c - g * 72;
            float v = 0.f;
            if (j < 64) v = P.w6[g][j * E_DIM + k];
            else if (j == 64) v = P.b6[g][k];
            P.Bkvf[k * R_STRIDE + c] = v;
        }
    } else if (bid < 522) {
        // Wct^T hi/lo [256][192] = (blockdiag(w7) @ mlp1w)^T; row 192 -> b_comp
        int row = bid - 329;
        int n = tid;
        if (row < 192) {
            int g = row >> 6, i = row & 63;
            const float* w7 = P.w7[g];
            float s = 0.f;
#pragma unroll 4
            for (int k = 0; k < 128; ++k)
                s = fmaf(w7[i * 128 + k], P.mlp1w[(size_t)(g * 128 + k) * 256 + n], s);
            bf16 h, l; split2(s, h, l);
            P.Wct_hi[n * T_STRIDE + row] = h;
            P.Wct_lo[n * T_STRIDE + row] = l;
        } else {
            float s = P.mlp1b[n];
            for (int g = 0; g < 3; ++g)
#pragma unroll 4
                for (int k = 0; k < 128; ++k)
                    s = fmaf(P.b7[g][k], P.mlp1w[(size_t)(g * 128 + k) * 256 + n], s);
            P.b_comp[n] = s;
        }
    } else if (bid < 650) {
        // mlp2w^T hi/lo [128][256]
        int n = bid - 522;
        int k = tid;
        float v = P.mlp2w[(size_t)k * 128 + n];
        bf16 h, l; split2(v, h, l);
        P.Wm2t_hi[n * 256 + k] = h;
        P.Wm2t_lo[n * 256 + k] = l;
    } else {
        // node q projection: one block per node row
        int b = bid - 650; // 0..1488
        int g = (b < 167) ? 0 : (b < 1048 ? 1 : 2);
        int row = b - (g == 0 ? 0 : (g == 1 ? 167 : 1048));
        int Dt = (g == 0) ? 167 : (g == 1 ? 881 : 441);
        const float* feat = P.feat[g] + (size_t)row * Dt;
        const float* w5 = P.w5[g];
        int col = tid & 63, ks = tid >> 6;
        float s = 0.f;
#pragma unroll 4
        for (int k = ks; k < Dt; k += 4)
            s = fmaf(feat[k], w5[k * Q_DIM + col], s);
        sh[ks * 64 + col] = s;
        __syncthreads();
        if (ks == 0)
            P.q_t[(size_t)b * Q_DIM + col] =
                sh[col] + sh[64 + col] + sh[128 + col] + sh[192 + col] + P.b5[g][col];
    }
}

// ---------------- W_R^T hi/lo [256][224] = (W12 @ Bkv)^T ; bR[216] = b12 @ Bkv ----------------
__global__ __launch_bounds__(256) void compose_wr_kernel(
    const float* __restrict__ W12f, const float* __restrict__ b12,
    const float* __restrict__ Bkvf,
    bf16* __restrict__ WRt_hi, bf16* __restrict__ WRt_lo, float* __restrict__ bR)
{
    int c = blockIdx.x;  // 0..255
    int t = threadIdx.x;
    const bf16 z = __float2bfloat16(0.f);
    if (c >= R_STRIDE) { // zero-pad B rows 216..255 (GEMM stages up to 256 rows)
        if (t < KP_HE) { WRt_hi[c * KP_HE + t] = z; WRt_lo[c * KP_HE + t] = z; }
        return;
    }
    __shared__ float col[128];
    if (t < 128) col[t] = Bkvf[t * R_STRIDE + c];
    __syncthreads();
    if (t < IN_F) {
        const float* wrow = W12f + (size_t)t * E_DIM;
        float s = 0.f;
#pragma unroll 4
        for (int k = 0; k < 128; ++k) s = fmaf(wrow[k], col[k], s);
        bf16 h, l; split2(s, h, l);
        WRt_hi[c * KP_HE + t] = h;
        WRt_lo[c * KP_HE + t] = l;
    } else if (t < KP_HE) { // zero-pad k 200..223
        WRt_hi[c * KP_HE + t] = z;
        WRt_lo[c * KP_HE + t] = z;
    } else if (t == KP_HE) {
        float s = 0.f;
        for (int k = 0; k < 128; ++k) s = fmaf(b12[k], col[k], s);
        bR[c] = s;
    }
}

// ---------------- split-precision MFMA GEMM, f32 A (split in staging), f32 C ----------------
template <bool GUARD, bool BIAS, bool RELU>
__global__ __launch_bounds__(256) void mfma_gemm_kernel(
    const float* __restrict__ A, int lda, int Kp, int Mvalid,
    const bf16* __restrict__ Bthg, const bf16* __restrict__ Btlg,
    const float* __restrict__ bias,
    float* __restrict__ C, int M, int N, int ldc)
{
    __shared__ bf16 Ah[128 * LDSD], Al[128 * LDSD], Bh[64 * LDSD], Bl[64 * LDSD];
    const int tid = threadIdx.x;
    const int bm = blockIdx.x * 128, bn = blockIdx.y * 64;
    const int lane = tid & 63, w = tid >> 6;
    const int kgrp = lane >> 4, lr = lane & 15;
    const int arow = tid >> 1, ahalf = (tid & 1) * 16;
    const int brow = tid >> 2, bq = (tid & 3) * 8;
    f32x4 acc[2][4] = {};

    for (int k0 = 0; k0 < Kp; k0 += 32) {
        {
            int row = bm + arow, kb = k0 + ahalf;
            float va[16];
            if (!GUARD || (row < Mvalid && kb + 16 <= lda)) {
                const float* ap = A + (size_t)row * lda + kb;
                *(float4*)&va[0]  = *(const float4*)ap;
                *(float4*)&va[4]  = *(const float4*)(ap + 4);
                *(float4*)&va[8]  = *(const float4*)(ap + 8);
                *(float4*)&va[12] = *(const float4*)(ap + 12);
            } else {
#pragma unroll
                for (int j = 0; j < 16; ++j) {
                    int k = kb + j;
                    va[j] = (row < Mvalid && k < lda) ? A[(size_t)row * lda + k] : 0.f;
                }
            }
            u16x8 H0, H1, L0, L1;
#pragma unroll
            for (int j = 0; j < 8; ++j) {
                unsigned short h, l;
                split2u(va[j], h, l);       H0[j] = h; L0[j] = l;
                split2u(va[8 + j], h, l);   H1[j] = h; L1[j] = l;
            }
            *(u16x8*)&Ah[arow * LDSD + ahalf] = H0;
            *(u16x8*)&Ah[arow * LDSD + ahalf + 8] = H1;
            *(u16x8*)&Al[arow * LDSD + ahalf] = L0;
            *(u16x8*)&Al[arow * LDSD + ahalf + 8] = L1;
            const size_t bbase = (size_t)(bn + brow) * Kp + k0 + bq;
            uint4 w0 = *(const uint4*)(Bthg + bbase);
            uint4 w1 = *(const uint4*)(Btlg + bbase);
            *(uint4*)&Bh[brow * LDSD + bq] = w0;
            *(uint4*)&Bl[brow * LDSD + bq] = w1;
        }
        __syncthreads();
        bf16x8s afh[2], afl[2], bfh[4], bfl[4];
#pragma unroll
        for (int mi = 0; mi < 2; ++mi) {
            int r = w * 32 + mi * 16 + lr;
            afh[mi] = *(const bf16x8s*)&Ah[r * LDSD + kgrp * 8];
            afl[mi] = *(const bf16x8s*)&Al[r * LDSD + kgrp * 8];
        }
#pragma unroll
        for (int ni = 0; ni < 4; ++ni) {
            int r = ni * 16 + lr;
            bfh[ni] = *(const bf16x8s*)&Bh[r * LDSD + kgrp * 8];
            bfl[ni] = *(const bf16x8s*)&Bl[r * LDSD + kgrp * 8];
        }
#pragma unroll
        for (int mi = 0; mi < 2; ++mi)
#pragma unroll
            for (int ni = 0; ni < 4; ++ni) {
                acc[mi][ni] = __builtin_amdgcn_mfma_f32_16x16x32_bf16(afh[mi], bfh[ni], acc[mi][ni], 0, 0, 0);
                acc[mi][ni] = __builtin_amdgcn_mfma_f32_16x16x32_bf16(afl[mi], bfh[ni], acc[mi][ni], 0, 0, 0);
                acc[mi][ni] = __builtin_amdgcn_mfma_f32_16x16x32_bf16(afh[mi], bfl[ni], acc[mi][ni], 0, 0, 0);
            }
        __syncthreads();
    }

    // epilogue: D col = lane&15, row = (lane>>4)*4 + reg  [m89-verified layout]
#pragma unroll
    for (int mi = 0; mi < 2; ++mi) {
#pragma unroll
        for (int ni = 0; ni < 4; ++ni) {
            int col = bn + ni * 16 + lr;
            float bv = 0.f;
            if (BIAS) bv = (col < N) ? bias[col] : 0.f;
            int row0 = bm + w * 32 + mi * 16 + kgrp * 4;
#pragma unroll
            for (int r = 0; r < 4; ++r) {
                float v = acc[mi][ni][r] + bv;
                if (RELU) v = fmaxf(v, 0.f);
                int row = row0 + r;
                if (row < M && col < N) C[(size_t)row * ldc + col] = v;
            }
        }
    }
}

// ================= binned CSR build (fixed-capacity slots) =================
__global__ __launch_bounds__(256) void bin_scatter_kernel(
    EdgeIdx S, EdgeIdx D, int* __restrict__ bincursor, unsigned* __restrict__ binbuf)
{
    int g = blockIdx.y;
    const int* src = S.p[g];
    const int* dst = D.p[g];
    __shared__ unsigned stage[ECHUNK];
    __shared__ int hist4[4][NBIN];
    __shared__ int hist[NBIN], off[NBIN], cur[NBIN], gbase[NBIN];
    int tid = threadIdx.x, lane = tid & 63, w = tid >> 6;
    for (int b = tid; b < 4 * NBIN; b += 256) (&hist4[0][0])[b] = 0;
    __syncthreads();

    int base = blockIdx.x * ECHUNK;
    int s[ECHUNK / 256], d[ECHUNK / 256];
#pragma unroll
    for (int k = 0; k < ECHUNK / 256; ++k) {
        int i = base + k * 256 + tid;
        if (i < E_EDGES) {
            s[k] = src[i];
            d[k] = dst[i];
            atomicAdd(&hist4[w][s[k] >> BIN_SHIFT], 1);
        } else s[k] = -1;
    }
    __syncthreads();
    if (w == 0) {
        int i1 = 64 + lane;
        int v0 = 0, v1 = 0;
        if (lane < NBIN) v0 = hist4[0][lane] + hist4[1][lane] + hist4[2][lane] + hist4[3][lane];
        if (i1 < NBIN) v1 = hist4[0][i1] + hist4[1][i1] + hist4[2][i1] + hist4[3][i1];
        int x0 = v0, x1 = v1;
#pragma unroll
        for (int o = 1; o < 64; o <<= 1) {
            int t0 = __shfl_up(x0, o, 64);
            int t1 = __shfl_up(x1, o, 64);
            if (lane >= o) { x0 += t0; x1 += t1; }
        }
        int tot0 = __shfl(x0, 63, 64);
        if (lane < NBIN) { hist[lane] = v0; off[lane] = x0 - v0; cur[lane] = x0 - v0; }
        if (i1 < NBIN) { hist[i1] = v1; off[i1] = tot0 + x1 - v1; cur[i1] = tot0 + x1 - v1; }
    }
    __syncthreads();
    if (tid < NBIN) gbase[tid] = hist[tid] ? atomicAdd(&bincursor[g * NBIN + tid], hist[tid]) : 0;
    __syncthreads();
#pragma unroll
    for (int k = 0; k < ECHUNK / 256; ++k) {
        if (s[k] >= 0) {
            int bin = s[k] >> BIN_SHIFT;
            int pos = atomicAdd(&cur[bin], 1);
            stage[pos] = ((unsigned)(s[k] & 511) << 10) | (unsigned)d[k];
        }
    }
    __syncthreads();
    size_t gslot = (size_t)g * NBIN * BINCAP;
    for (int b = w; b < NBIN; b += 4) {
        int len = hist[b];
        if (!len) continue;
        int gb = gbase[b];
        int avail = BINCAP - gb;
        if (avail <= 0) continue;
        if (len > avail) len = avail;
        int lo = off[b];
        size_t obase = gslot + (size_t)b * BINCAP + gb;
        for (int j = lane; j < len; j += 64)
            binbuf[obase + j] = stage[lo + j];
    }
}

__global__ __launch_bounds__(256) void bin_csr_kernel(
    const unsigned* __restrict__ binbuf, const int* __restrict__ bincursor,
    int2* __restrict__ rows2_all, int* __restrict__ ebuf)
{
    int b = blockIdx.x, g = blockIdx.y;
    int cnt = min(bincursor[g * NBIN + b], BINCAP);
    size_t sbase = ((size_t)g * NBIN + b) * BINCAP;
    int h0 = b << BIN_SHIFT;
    int hN = min(512, N_HE - h0);
    int ebase_rel = b * BINCAP;
    int2* rows2 = rows2_all + g * N_HE;
    __shared__ int hist[512], cur[512], cs[8];
    int tid = threadIdx.x, lane = tid & 63, w = tid >> 6;
    hist[tid] = 0; hist[tid + 256] = 0;
    __syncthreads();
    for (int i = tid; i < cnt; i += 256)
        atomicAdd(&hist[binbuf[sbase + i] >> 10], 1);
    __syncthreads();
#pragma unroll
    for (int c2 = 0; c2 < 2; ++c2) {
        int c = w * 2 + c2, idx = c * 64 + lane;
        int v = hist[idx], x = v;
#pragma unroll
        for (int o = 1; o < 64; o <<= 1) {
            int t = __shfl_up(x, o, 64);
            if (lane >= o) x += t;
        }
        cur[idx] = x - v;
        if (lane == 63) cs[c] = x;
    }
    __syncthreads();
    if (tid == 0) {
        int run = 0;
#pragma unroll
        for (int c = 0; c < 8; ++c) { int t = cs[c]; cs[c] = run; run += t; }
    }
    __syncthreads();
#pragma unroll
    for (int c2 = 0; c2 < 2; ++c2) {
        int c = w * 2 + c2, idx = c * 64 + lane;
        int e = cur[idx] + cs[c];
        cur[idx] = e;
        if (idx < hN) rows2[h0 + idx] = make_int2(ebase_rel + e, ebase_rel + e + hist[idx]);
    }
    __syncthreads();
    for (int i = tid; i < cnt; i += 256) {
        unsigned p = binbuf[sbase + i];
        int pos = atomicAdd(&cur[p >> 10], 1);
        ebuf[sbase + pos] = (int)(p & 1023u);
    }
}

// ---------------- attention on reduced 64-dim states (2-edge, f32 T out) ----------------
__global__ __launch_bounds__(256) void attn_kernel(
    const float* __restrict__ R,        // [N_HE][216]
    const float* __restrict__ q_t,      // [1489][64]
    const int2* __restrict__ rows2_all, // [3][N_HE] group-relative (start,end)
    const int* __restrict__ ebuf_all,   // [3][NBIN*BINCAP]
    float* __restrict__ T)              // [M_PAD][192] f32
{
    int wid = blockIdx.x * 4 + (threadIdx.x >> 6);
    int lane = threadIdx.x & 63;
    int g = wid / N_HE;
    int h = wid - g * N_HE;
    const int toff_tab[3] = {0, 167, 1048};
    const float* qt = q_t + (size_t)toff_tab[g] * Q_DIM;
    const int* ebuf = ebuf_all + (size_t)g * NBIN * BINCAP;
    int2 se = rows2_all[g * N_HE + h];
    int start = se.x, end = se.y;

    int sub = lane >> 4, sl = lane & 15;
    const float* Rrow = R + (size_t)h * R_STRIDE + g * 72;
    float4 r4 = *reinterpret_cast<const float4*>(Rrow + sl * 4);
    float ch = Rrow[64];

    float m = -INFINITY, denom = 0.f;
    float acc0 = 0.f, acc1 = 0.f, acc2 = 0.f, acc3 = 0.f;

    for (int i0 = start + sub * 2; i0 < end; i0 += 8) {
        bool ok1 = (i0 + 1) < end;
        int d0 = ebuf[i0];
        int d1 = ebuf[ok1 ? i0 + 1 : i0];
        float4 t0 = *reinterpret_cast<const float4*>(qt + (size_t)d0 * Q_DIM + sl * 4);
        float4 t1 = *reinterpret_cast<const float4*>(qt + (size_t)d1 * Q_DIM + sl * 4);
        float p0 = t0.x * r4.x;
        p0 = fmaf(t0.y, r4.y, p0); p0 = fmaf(t0.z, r4.z, p0); p0 = fmaf(t0.w, r4.w, p0);
        float p1 = t1.x * r4.x;
        p1 = fmaf(t1.y, r4.y, p1); p1 = fmaf(t1.z, r4.z, p1); p1 = fmaf(t1.w, r4.w, p1);
#pragma unroll
        for (int mask = 1; mask < 16; mask <<= 1) {
            p0 += __shfl_xor(p0, mask, 64);
            p1 += __shfl_xor(p1, mask, 64);
        }
        float s0 = (p0 + ch) * SCALE; s0 = s0 > 0.f ? s0 : 0.01f * s0;
        float s1 = (p1 + ch) * SCALE; s1 = s1 > 0.f ? s1 : 0.01f * s1;
        if (!ok1) s1 = -INFINITY;
        float newm = fmaxf(fmaxf(s0, s1), m);
        float sc = __expf(m - newm);
        float w0 = __expf(s0 - newm);
        float w1 = __expf(s1 - newm);
        denom = fmaf(denom, sc, w0 + w1);
        acc0 = fmaf(w0, t0.x, fmaf(w1, t1.x, acc0 * sc));
        acc1 = fmaf(w0, t0.y, fmaf(w1, t1.y, acc1 * sc));
        acc2 = fmaf(w0, t0.z, fmaf(w1, t1.z, acc2 * sc));
        acc3 = fmaf(w0, t0.w, fmaf(w1, t1.w, acc3 * sc));
        m = newm;
    }

    float om = fmaxf(m, __shfl_xor(m, 16, 64));
    om = fmaxf(om, __shfl_xor(om, 32, 64));
    float f = (denom > 0.f) ? __expf(m - om) : 0.f;
    float d = denom * f;
    d += __shfl_xor(d, 16, 64);
    d += __shfl_xor(d, 32, 64);
    float a0 = acc0 * f, a1 = acc1 * f, a2 = acc2 * f, a3 = acc3 * f;
    a0 += __shfl_xor(a0, 16, 64); a0 += __shfl_xor(a0, 32, 64);
    a1 += __shfl_xor(a1, 16, 64); a1 += __shfl_xor(a1, 32, 64);
    a2 += __shfl_xor(a2, 16, 64); a2 += __shfl_xor(a2, 32, 64);
    a3 += __shfl_xor(a3, 16, 64); a3 += __shfl_xor(a3, 32, 64);
    if (sub == 0) {
        float rden = 1.f / fmaxf(d, 1e-20f);
        float4 o = {a0 * rden, a1 * rden, a2 * rden, a3 * rden};
        *reinterpret_cast<float4*>(T + (size_t)h * T_STRIDE + g * 64 + sl * 4) = o;
    }
}

// ---------------- launch ----------------
extern "C" void kernel_launch(void* const* d_in, const int* in_sizes, int n_in,
                              void* d_out, int out_size, void* d_ws, size_t ws_size,
                              hipStream_t stream)
{
    const float* he_feat = (const float*)d_in[0];
    float* out = (float*)d_out;

    EdgeIdx Esrc, Edst;
    for (int g = 0; g < 3; ++g) {
        Esrc.p[g] = (const int*)d_in[34 + 2 * g];
        Edst.p[g] = (const int*)d_in[35 + 2 * g];
    }

    char* base = (char*)d_ws;
    size_t off = 0;
    auto alloc = [&](size_t bytes) -> void* {
        void* r = (void*)(base + off);
        off = (off + bytes + 255) & ~(size_t)255;
        return r;
    };
    // ---- persistent small region (~2.4 MB) ----
    float* W12f = (float*)alloc(IN_F * E_DIM * 4);
    float* b12 = (float*)alloc(E_DIM * 4);
    float* Bkvf = (float*)alloc(E_DIM * R_STRIDE * 4);
    bf16* WRt_hi = (bf16*)alloc(256 * KP_HE * 2);
    bf16* WRt_lo = (bf16*)alloc(256 * KP_HE * 2);
    float* bR = (float*)alloc(R_STRIDE * 4);
    bf16* Wct_hi = (bf16*)alloc(256 * T_STRIDE * 2);
    bf16* Wct_lo = (bf16*)alloc(256 * T_STRIDE * 2);
    float* b_comp = (float*)alloc(256 * 4);
    bf16* Wm2t_hi = (bf16*)alloc(128 * 256 * 2);
    bf16* Wm2t_lo = (bf16*)alloc(128 * 256 * 2);
    float* q_t = (float*)alloc(N_NODES * Q_DIM * 4);
    int* bincursor = (int*)alloc(3 * NBIN * 4);
    int2* rows2 = (int2*)alloc((size_t)3 * N_HE * 8);
    // ---- big buffers with lifetime overlays (~99.5 MB total) ----
    size_t T_start = off;
    float* T = (float*)alloc((size_t)M_PAD * T_STRIDE * 4);    // 38.4 MB [attn -> mlp1]
    size_t R_start = off;
    float* R = (float*)alloc((size_t)N_HE * R_STRIDE * 4);     // 43.2 MB [R-gemm -> attn]
    int* ebuf = (int*)alloc((size_t)3 * NBIN * BINCAP * 4);    // 15.4 MB [bin_csr -> attn]
    // overlays:
    unsigned* binbuf = (unsigned*)(base + T_start);             // 15.4 MB [scatter -> csr], dead before attn writes T
    float* h1 = (float*)(base + R_start);                       // 51.2 MB [mlp1 -> mlp2], over dead R+ebuf

    hipMemsetAsync(bincursor, 0, 3 * NBIN * 4, stream);

    // ---- binned CSR build ----
    {
        dim3 grid((E_EDGES + ECHUNK - 1) / ECHUNK, 3);
        bin_scatter_kernel<<<grid, 256, 0, stream>>>(Esrc, Edst, bincursor, binbuf);
        bin_csr_kernel<<<dim3(NBIN, 3), 256, 0, stream>>>(binbuf, bincursor, rows2, ebuf);
    }

    // ---- fused prep ----
    PrepArgs P;
    P.w1w = (const float*)d_in[4]; P.w1b = (const float*)d_in[5];
    P.w2w = (const float*)d_in[6]; P.w2b = (const float*)d_in[7];
    P.W12f = W12f; P.b12 = b12;
    for (int g = 0; g < 3; ++g) {
        P.w6[g] = (const float*)d_in[18 + 4 * g];
        P.b6[g] = (const float*)d_in[19 + 4 * g];
        P.w7[g] = (const float*)d_in[20 + 4 * g];
        P.b7[g] = (const float*)d_in[21 + 4 * g];
        P.feat[g] = (const float*)d_in[1 + g];
        P.w5[g] = (const float*)d_in[12 + 2 * g];
        P.b5[g] = (const float*)d_in[13 + 2 * g];
    }
    P.Bkvf = Bkvf;
    P.mlp1w = (const float*)d_in[30]; P.mlp1b = (const float*)d_in[31];
    P.Wct_hi = Wct_hi; P.Wct_lo = Wct_lo; P.b_comp = b_comp;
    P.mlp2w = (const float*)d_in[32];
    P.Wm2t_hi = Wm2t_hi; P.Wm2t_lo = Wm2t_lo;
    P.q_t = q_t;
    prep_fused_kernel<<<650 + N_NODES, 256, 0, stream>>>(P);
    compose_wr_kernel<<<256, 256, 0, stream>>>(W12f, b12, Bkvf, WRt_hi, WRt_lo, bR);

    const int MB = M_PAD / 128; // 391
    const float* mlp2b = (const float*)d_in[33];
    // R = he_feat @ W_R + bR  (guarded: he_feat is [50000][200] unpadded)
    mfma_gemm_kernel<true, true, false><<<dim3(MB, 4), 256, 0, stream>>>(
        he_feat, IN_F, KP_HE, N_HE, WRt_hi, WRt_lo, bR, R, N_HE, R_STRIDE, R_STRIDE);
    // attention -> T f32 [M_PAD][192]  (overwrites binbuf: dead)
    attn_kernel<<<(3 * N_HE) / 4, 256, 0, stream>>>(R, q_t, rows2, ebuf, T);
    // h1 = relu(T @ W_comp + b_comp)  (overwrites R/ebuf: dead)
    mfma_gemm_kernel<false, true, true><<<dim3(MB, 4), 256, 0, stream>>>(
        T, T_STRIDE, T_STRIDE, M_PAD, Wct_hi, Wct_lo, b_comp, h1, M_PAD, 256, 256);
    // out = relu(h1 @ mlp2w + mlp2b)
    mfma_gemm_kernel<false, true, true><<<dim3(MB, 2), 256, 0, stream>>>(
        h1, 256, 256, M_PAD, Wm2t_hi, Wm2t_lo, mlp2b, out, N_HE, E_DIM, E_DIM);
}

// Round 11
// 288.503 us; speedup vs baseline: 1.3911x; 1.0800x over previous
//
#include <hip/hip_runtime.h>
#include <hip/hip_bf16.h>

typedef __hip_bfloat16 bf16;
typedef float f32x4 __attribute__((ext_vector_type(4)));
typedef short bf16x8s __attribute__((ext_vector_type(8)));
typedef unsigned short u16x8 __attribute__((ext_vector_type(8)));

constexpr int N_HE = 50000;
constexpr int M_PAD = 50048;           // 391 * 128
constexpr int E_EDGES = 1200000;
constexpr int IN_F = 200;
constexpr int KP_HE = 224;             // 200 padded to x32
constexpr int HE_DIM = 512;
constexpr int E_DIM = 128;
constexpr int Q_DIM = 64;
constexpr float SL2E = 0.125f * 1.44269504088896f; // SCALE * log2(e), folded into W_R/bR
constexpr int N_NODES = 1489;
constexpr int R_STRIDE = 216;          // 3 x 72 (64 r + 1 c + 7 pad)
constexpr int T_STRIDE = 192;          // 3 x 64
constexpr int LDSD = 40;               // LDS row stride (bf16) for GEMM staging
constexpr int NBIN = 98;               // ceil(50000/512) bins per group
constexpr int BIN_SHIFT = 9;           // 512 hyperedges per bin
constexpr int ECHUNK = 4096;           // edges per bin_scatter block
constexpr int BINCAP = 13056;          // mean 12288 + 7 sigma, clamp-guarded

struct EdgeIdx { const int* p[3]; };

__device__ __forceinline__ void split2(float v, bf16& h, bf16& l)
{
    bf16 hb = __float2bfloat16(v);
    h = hb;
    l = __float2bfloat16(v - __bfloat162float(hb));
}
__device__ __forceinline__ void split2u(float v, unsigned short& h, unsigned short& l)
{
    bf16 hb = __float2bfloat16(v);
    bf16 lb = __float2bfloat16(v - __bfloat162float(hb));
    h = *reinterpret_cast<unsigned short*>(&hb);
    l = *reinterpret_cast<unsigned short*>(&lb);
}
__device__ __forceinline__ float exp2_fast(float x)
{
    float r;
    asm("v_exp_f32 %0, %1" : "=v"(r) : "v"(x));
    return r;
}

// ================= fused prep (5 kernels + bincursor zeroing, block-range dispatch) =================
struct PrepArgs {
    const float *w1w, *w1b, *w2w, *w2b;
    float *W12f, *b12;
    const float *w6[3], *b6[3];
    float *Bkvf;
    const float *w7[3], *b7[3];
    const float *mlp1w, *mlp1b;
    bf16 *Wct_hi, *Wct_lo;
    float *b_comp;
    const float *mlp2w;
    bf16 *Wm2t_hi, *Wm2t_lo;
    const float *feat[3], *w5[3], *b5[3];
    float *q_t;
    int *bincursor;
};

__global__ __launch_bounds__(256) void prep_fused_kernel(PrepArgs P)
{
    __shared__ float sh[256];
    int bid = blockIdx.x, tid = threadIdx.x;
    if (bid < 201) {
        // W12f[200][128] = w1w @ w2w (f32); row 200 -> b12
        int row = bid;
        int col = tid & 127, ks = tid >> 7;
        const float* a = (row < IN_F) ? (P.w1w + (size_t)row * HE_DIM) : P.w1b;
        float s = 0.f;
#pragma unroll 4
        for (int k = ks; k < HE_DIM; k += 2)
            s = fmaf(a[k], P.w2w[k * E_DIM + col], s);
        sh[ks * 128 + col] = s;
        __syncthreads();
        if (ks == 0) {
            float v = sh[col] + sh[128 + col];
            if (row < IN_F) P.W12f[row * E_DIM + col] = v;
            else P.b12[col] = v + P.w2b[col];
        }
    } else if (bid < 329) {
        // Bkvf[128][216] f32: col c=g*72+j -> w6_g^T / b6_g / 0
        int k = bid - 201;
        int c = tid;
        if (c < R_STRIDE) {
            int g = c / 72, j = c - g * 72;
            float v = 0.f;
            if (j < 64) v = P.w6[g][j * E_DIM + k];
            else if (j == 64) v = P.b6[g][k];
            P.Bkvf[k * R_STRIDE + c] = v;
        }
    } else if (bid < 522) {
        // Wct^T hi/lo [256][192] = (blockdiag(w7) @ mlp1w)^T; row 192 -> b_comp
        int row = bid - 329;
        int n = tid;
        if (row < 192) {
            int g = row >> 6, i = row & 63;
            const float* w7 = P.w7[g];
            float s = 0.f;
#pragma unroll 4
            for (int k = 0; k < 128; ++k)
                s = fmaf(w7[i * 128 + k], P.mlp1w[(size_t)(g * 128 + k) * 256 + n], s);
            bf16 h, l; split2(s, h, l);
            P.Wct_hi[n * T_STRIDE + row] = h;
            P.Wct_lo[n * T_STRIDE + row] = l;
        } else {
            float s = P.mlp1b[n];
            for (int g = 0; g < 3; ++g)
#pragma unroll 4
                for (int k = 0; k < 128; ++k)
                    s = fmaf(P.b7[g][k], P.mlp1w[(size_t)(g * 128 + k) * 256 + n], s);
            P.b_comp[n] = s;
        }
    } else if (bid < 650) {
        // mlp2w^T hi/lo [128][256]
        int n = bid - 522;
        int k = tid;
        float v = P.mlp2w[(size_t)k * 128 + n];
        bf16 h, l; split2(v, h, l);
        P.Wm2t_hi[n * 256 + k] = h;
        P.Wm2t_lo[n * 256 + k] = l;
    } else if (bid < 650 + N_NODES) {
        // node q projection: one block per node row
        int b = bid - 650; // 0..1488
        int g = (b < 167) ? 0 : (b < 1048 ? 1 : 2);
        int row = b - (g == 0 ? 0 : (g == 1 ? 167 : 1048));
        int Dt = (g == 0) ? 167 : (g == 1 ? 881 : 441);
        const float* feat = P.feat[g] + (size_t)row * Dt;
        const float* w5 = P.w5[g];
        int col = tid & 63, ks = tid >> 6;
        float s = 0.f;
#pragma unroll 4
        for (int k = ks; k < Dt; k += 4)
            s = fmaf(feat[k], w5[k * Q_DIM + col], s);
        sh[ks * 64 + col] = s;
        __syncthreads();
        if (ks == 0)
            P.q_t[(size_t)b * Q_DIM + col] =
                sh[col] + sh[64 + col] + sh[128 + col] + sh[192 + col] + P.b5[g][col];
    } else {
        // zero bincursor (294 ints over 2 blocks)
        int idx = (bid - (650 + N_NODES)) * 256 + tid;
        if (idx < 3 * NBIN) P.bincursor[idx] = 0;
    }
}

// ================= binned CSR build (fixed-capacity slots) =================
__global__ __launch_bounds__(256) void bin_scatter_kernel(
    EdgeIdx S, EdgeIdx D, int* __restrict__ bincursor, unsigned* __restrict__ binbuf)
{
    int g = blockIdx.y;
    const int* src = S.p[g];
    const int* dst = D.p[g];
    __shared__ unsigned stage[ECHUNK];
    __shared__ int hist4[4][NBIN];
    __shared__ int hist[NBIN], off[NBIN], cur[NBIN], gbase[NBIN];
    int tid = threadIdx.x, lane = tid & 63, w = tid >> 6;
    for (int b = tid; b < 4 * NBIN; b += 256) (&hist4[0][0])[b] = 0;
    __syncthreads();

    int base = blockIdx.x * ECHUNK;
    int s[ECHUNK / 256], d[ECHUNK / 256];
#pragma unroll
    for (int k = 0; k < ECHUNK / 256; ++k) {
        int i = base + k * 256 + tid;
        if (i < E_EDGES) {
            s[k] = src[i];
            d[k] = dst[i];
            atomicAdd(&hist4[w][s[k] >> BIN_SHIFT], 1);
        } else s[k] = -1;
    }
    __syncthreads();
    if (w == 0) {
        int i1 = 64 + lane;
        int v0 = 0, v1 = 0;
        if (lane < NBIN) v0 = hist4[0][lane] + hist4[1][lane] + hist4[2][lane] + hist4[3][lane];
        if (i1 < NBIN) v1 = hist4[0][i1] + hist4[1][i1] + hist4[2][i1] + hist4[3][i1];
        int x0 = v0, x1 = v1;
#pragma unroll
        for (int o = 1; o < 64; o <<= 1) {
            int t0 = __shfl_up(x0, o, 64);
            int t1 = __shfl_up(x1, o, 64);
            if (lane >= o) { x0 += t0; x1 += t1; }
        }
        int tot0 = __shfl(x0, 63, 64);
        if (lane < NBIN) { hist[lane] = v0; off[lane] = x0 - v0; cur[lane] = x0 - v0; }
        if (i1 < NBIN) { hist[i1] = v1; off[i1] = tot0 + x1 - v1; cur[i1] = tot0 + x1 - v1; }
    }
    __syncthreads();
    if (tid < NBIN) gbase[tid] = hist[tid] ? atomicAdd(&bincursor[g * NBIN + tid], hist[tid]) : 0;
    __syncthreads();
#pragma unroll
    for (int k = 0; k < ECHUNK / 256; ++k) {
        if (s[k] >= 0) {
            int bin = s[k] >> BIN_SHIFT;
            int pos = atomicAdd(&cur[bin], 1);
            stage[pos] = ((unsigned)(s[k] & 511) << 10) | (unsigned)d[k];
        }
    }
    __syncthreads();
    size_t gslot = (size_t)g * NBIN * BINCAP;
    for (int b = w; b < NBIN; b += 4) {
        int len = hist[b];
        if (!len) continue;
        int gb = gbase[b];
        int avail = BINCAP - gb;
        if (avail <= 0) continue;
        if (len > avail) len = avail;
        int lo = off[b];
        size_t obase = gslot + (size_t)b * BINCAP + gb;
        for (int j = lane; j < len; j += 64)
            binbuf[obase + j] = stage[lo + j];
    }
}

// ---------------- fused: bin_csr (294 blocks) + compose_wr (256 blocks) ----------------
__global__ __launch_bounds__(256) void csr_wr_fused_kernel(
    const unsigned* __restrict__ binbuf, const int* __restrict__ bincursor,
    int2* __restrict__ rows2_all, int* __restrict__ ebuf,
    const float* __restrict__ W12f, const float* __restrict__ b12,
    const float* __restrict__ Bkvf,
    bf16* __restrict__ WRt_hi, bf16* __restrict__ WRt_lo, float* __restrict__ bR)
{
    __shared__ int hist[512], cur[512], cs[8];
    __shared__ float fcol[128];
    int bid = blockIdx.x, tid = threadIdx.x;
    if (bid < 3 * NBIN) {
        // ---- bin_csr ----
        int g = bid / NBIN, b = bid - g * NBIN;
        int cnt = min(bincursor[g * NBIN + b], BINCAP);
        size_t sbase = ((size_t)g * NBIN + b) * BINCAP;
        int h0 = b << BIN_SHIFT;
        int hN = min(512, N_HE - h0);
        int ebase_rel = b * BINCAP;
        int2* rows2 = rows2_all + g * N_HE;
        int lane = tid & 63, w = tid >> 6;
        hist[tid] = 0; hist[tid + 256] = 0;
        __syncthreads();
        for (int i = tid; i < cnt; i += 256)
            atomicAdd(&hist[binbuf[sbase + i] >> 10], 1);
        __syncthreads();
#pragma unroll
        for (int c2 = 0; c2 < 2; ++c2) {
            int c = w * 2 + c2, idx = c * 64 + lane;
            int v = hist[idx], x = v;
#pragma unroll
            for (int o = 1; o < 64; o <<= 1) {
                int t = __shfl_up(x, o, 64);
                if (lane >= o) x += t;
            }
            cur[idx] = x - v;
            if (lane == 63) cs[c] = x;
        }
        __syncthreads();
        if (tid == 0) {
            int run = 0;
#pragma unroll
            for (int c = 0; c < 8; ++c) { int t = cs[c]; cs[c] = run; run += t; }
        }
        __syncthreads();
#pragma unroll
        for (int c2 = 0; c2 < 2; ++c2) {
            int c = w * 2 + c2, idx = c * 64 + lane;
            int e = cur[idx] + cs[c];
            cur[idx] = e;
            if (idx < hN) rows2[h0 + idx] = make_int2(ebase_rel + e, ebase_rel + e + hist[idx]);
        }
        __syncthreads();
        for (int i = tid; i < cnt; i += 256) {
            unsigned p = binbuf[sbase + i];
            int pos = atomicAdd(&cur[p >> 10], 1);
            ebuf[sbase + pos] = (int)((p & 1023u) << 8); // byte offset into q_t rows (256 B/row)
        }
    } else {
        // ---- compose W_R^T hi/lo [256][224] = (W12 @ Bkv)^T * SL2E ; bR = b12 @ Bkv * SL2E ----
        int c = bid - 3 * NBIN;  // 0..255
        const bf16 z = __float2bfloat16(0.f);
        if (c >= R_STRIDE) {
            if (tid < KP_HE) { WRt_hi[c * KP_HE + tid] = z; WRt_lo[c * KP_HE + tid] = z; }
            return;
        }
        if (tid < 128) fcol[tid] = Bkvf[tid * R_STRIDE + c];
        __syncthreads();
        if (tid < IN_F) {
            const float* wrow = W12f + (size_t)tid * E_DIM;
            float s = 0.f;
#pragma unroll 4
            for (int k = 0; k < 128; ++k) s = fmaf(wrow[k], fcol[k], s);
            bf16 h, l; split2(s * SL2E, h, l);
            WRt_hi[c * KP_HE + tid] = h;
            WRt_lo[c * KP_HE + tid] = l;
        } else if (tid < KP_HE) {
            WRt_hi[c * KP_HE + tid] = z;
            WRt_lo[c * KP_HE + tid] = z;
        } else if (tid == KP_HE) {
            float s = 0.f;
            for (int k = 0; k < 128; ++k) s = fmaf(b12[k], fcol[k], s);
            bR[c] = s * SL2E;
        }
    }
}

// ---------------- split-precision MFMA GEMM, f32 A (split in staging), f32 C ----------------
template <bool GUARD, bool BIAS, bool RELU>
__global__ __launch_bounds__(256) void mfma_gemm_kernel(
    const float* __restrict__ A, int lda, int Kp, int Mvalid,
    const bf16* __restrict__ Bthg, const bf16* __restrict__ Btlg,
    const float* __restrict__ bias,
    float* __restrict__ C, int M, int N, int ldc)
{
    __shared__ bf16 Ah[128 * LDSD], Al[128 * LDSD], Bh[64 * LDSD], Bl[64 * LDSD];
    const int tid = threadIdx.x;
    const int bm = blockIdx.x * 128, bn = blockIdx.y * 64;
    const int lane = tid & 63, w = tid >> 6;
    const int kgrp = lane >> 4, lr = lane & 15;
    const int arow = tid >> 1, ahalf = (tid & 1) * 16;
    const int brow = tid >> 2, bq = (tid & 3) * 8;
    f32x4 acc[2][4] = {};

    for (int k0 = 0; k0 < Kp; k0 += 32) {
        {
            int row = bm + arow, kb = k0 + ahalf;
            float va[16];
            if (!GUARD || (row < Mvalid && kb + 16 <= lda)) {
                const float* ap = A + (size_t)row * lda + kb;
                *(float4*)&va[0]  = *(const float4*)ap;
                *(float4*)&va[4]  = *(const float4*)(ap + 4);
                *(float4*)&va[8]  = *(const float4*)(ap + 8);
                *(float4*)&va[12] = *(const float4*)(ap + 12);
            } else {
#pragma unroll
                for (int j = 0; j < 16; ++j) {
                    int k = kb + j;
                    va[j] = (row < Mvalid && k < lda) ? A[(size_t)row * lda + k] : 0.f;
                }
            }
            u16x8 H0, H1, L0, L1;
#pragma unroll
            for (int j = 0; j < 8; ++j) {
                unsigned short h, l;
                split2u(va[j], h, l);       H0[j] = h; L0[j] = l;
                split2u(va[8 + j], h, l);   H1[j] = h; L1[j] = l;
            }
            *(u16x8*)&Ah[arow * LDSD + ahalf] = H0;
            *(u16x8*)&Ah[arow * LDSD + ahalf + 8] = H1;
            *(u16x8*)&Al[arow * LDSD + ahalf] = L0;
            *(u16x8*)&Al[arow * LDSD + ahalf + 8] = L1;
            const size_t bbase = (size_t)(bn + brow) * Kp + k0 + bq;
            uint4 w0 = *(const uint4*)(Bthg + bbase);
            uint4 w1 = *(const uint4*)(Btlg + bbase);
            *(uint4*)&Bh[brow * LDSD + bq] = w0;
            *(uint4*)&Bl[brow * LDSD + bq] = w1;
        }
        __syncthreads();
        bf16x8s afh[2], afl[2], bfh[4], bfl[4];
#pragma unroll
        for (int mi = 0; mi < 2; ++mi) {
            int r = w * 32 + mi * 16 + lr;
            afh[mi] = *(const bf16x8s*)&Ah[r * LDSD + kgrp * 8];
            afl[mi] = *(const bf16x8s*)&Al[r * LDSD + kgrp * 8];
        }
#pragma unroll
        for (int ni = 0; ni < 4; ++ni) {
            int r = ni * 16 + lr;
            bfh[ni] = *(const bf16x8s*)&Bh[r * LDSD + kgrp * 8];
            bfl[ni] = *(const bf16x8s*)&Bl[r * LDSD + kgrp * 8];
        }
#pragma unroll
        for (int mi = 0; mi < 2; ++mi)
#pragma unroll
            for (int ni = 0; ni < 4; ++ni) {
                acc[mi][ni] = __builtin_amdgcn_mfma_f32_16x16x32_bf16(afh[mi], bfh[ni], acc[mi][ni], 0, 0, 0);
                acc[mi][ni] = __builtin_amdgcn_mfma_f32_16x16x32_bf16(afl[mi], bfh[ni], acc[mi][ni], 0, 0, 0);
                acc[mi][ni] = __builtin_amdgcn_mfma_f32_16x16x32_bf16(afh[mi], bfl[ni], acc[mi][ni], 0, 0, 0);
            }
        __syncthreads();
    }

    // epilogue: D col = lane&15, row = (lane>>4)*4 + reg  [m89-verified layout]
#pragma unroll
    for (int mi = 0; mi < 2; ++mi) {
#pragma unroll
        for (int ni = 0; ni < 4; ++ni) {
            int col = bn + ni * 16 + lr;
            float bv = 0.f;
            if (BIAS) bv = (col < N) ? bias[col] : 0.f;
            int row0 = bm + w * 32 + mi * 16 + kgrp * 4;
#pragma unroll
            for (int r = 0; r < 4; ++r) {
                float v = acc[mi][ni][r] + bv;
                if (RELU) v = fmaxf(v, 0.f);
                int row = row0 + r;
                if (row < M && col < N) C[(size_t)row * ldc + col] = v;
            }
        }
    }
}

// ---------------- attention: fixed-max, log2-domain, 2-edge ----------------
__global__ __launch_bounds__(256) void attn_kernel(
    const float* __restrict__ R,        // [N_HE][216], scores pre-scaled by SL2E
    const float* __restrict__ q_t,      // [1489][64]
    const int2* __restrict__ rows2_all, // [3][N_HE] group-relative (start,end)
    const int* __restrict__ ebuf_all,   // [3][NBIN*BINCAP], holds d<<8 byte offsets
    float* __restrict__ T)              // [M_PAD][192] f32
{
    int wid = blockIdx.x * 4 + (threadIdx.x >> 6);
    int lane = threadIdx.x & 63;
    int g = wid / N_HE;
    int h = wid - g * N_HE;
    const int toff_tab[3] = {0, 167, 1048};
    const char* qb = (const char*)(q_t + (size_t)toff_tab[g] * Q_DIM);
    const int* ebuf = ebuf_all + (size_t)g * NBIN * BINCAP;
    int2 se = rows2_all[g * N_HE + h];
    int start = se.x, end = se.y;

    int sub = lane >> 4, sl = lane & 15;
    const float* Rrow = R + (size_t)h * R_STRIDE + g * 72;
    float4 r4 = *reinterpret_cast<const float4*>(Rrow + sl * 4);
    float ch = Rrow[64];
    int slo = sl * 16;

    float denom = 0.f;
    float acc0 = 0.f, acc1 = 0.f, acc2 = 0.f, acc3 = 0.f;

    for (int i0 = start + sub * 2; i0 < end; i0 += 8) {
        bool ok1 = (i0 + 1) < end;
        int o0 = ebuf[i0];
        int o1 = ebuf[ok1 ? i0 + 1 : i0];
        float4 t0 = *reinterpret_cast<const float4*>(qb + o0 + slo);
        float4 t1 = *reinterpret_cast<const float4*>(qb + o1 + slo);
        float p0 = t0.x * r4.x;
        p0 = fmaf(t0.y, r4.y, p0); p0 = fmaf(t0.z, r4.z, p0); p0 = fmaf(t0.w, r4.w, p0);
        float p1 = t1.x * r4.x;
        p1 = fmaf(t1.y, r4.y, p1); p1 = fmaf(t1.z, r4.z, p1); p1 = fmaf(t1.w, r4.w, p1);
#pragma unroll
        for (int mask = 1; mask < 16; mask <<= 1) {
            p0 += __shfl_xor(p0, mask, 64);
            p1 += __shfl_xor(p1, mask, 64);
        }
        float s0 = p0 + ch; s0 = fmaxf(s0, 0.01f * s0);   // leaky_relu (scores pre-scaled)
        float s1 = p1 + ch; s1 = fmaxf(s1, 0.01f * s1);
        float w0 = exp2_fast(s0);
        float w1 = ok1 ? exp2_fast(s1) : 0.f;
        denom += w0 + w1;
        acc0 = fmaf(w0, t0.x, fmaf(w1, t1.x, acc0));
        acc1 = fmaf(w0, t0.y, fmaf(w1, t1.y, acc1));
        acc2 = fmaf(w0, t0.z, fmaf(w1, t1.z, acc2));
        acc3 = fmaf(w0, t0.w, fmaf(w1, t1.w, acc3));
    }

    // sum across the 4 subgroups
    denom += __shfl_xor(denom, 16, 64); denom += __shfl_xor(denom, 32, 64);
    acc0 += __shfl_xor(acc0, 16, 64); acc0 += __shfl_xor(acc0, 32, 64);
    acc1 += __shfl_xor(acc1, 16, 64); acc1 += __shfl_xor(acc1, 32, 64);
    acc2 += __shfl_xor(acc2, 16, 64); acc2 += __shfl_xor(acc2, 32, 64);
    acc3 += __shfl_xor(acc3, 16, 64); acc3 += __shfl_xor(acc3, 32, 64);
    if (sub == 0) {
        float rden = 1.f / fmaxf(denom, 1e-20f);
        float4 o = {acc0 * rden, acc1 * rden, acc2 * rden, acc3 * rden};
        *reinterpret_cast<float4*>(T + (size_t)h * T_STRIDE + g * 64 + sl * 4) = o;
    }
}

// ---------------- launch ----------------
extern "C" void kernel_launch(void* const* d_in, const int* in_sizes, int n_in,
                              void* d_out, int out_size, void* d_ws, size_t ws_size,
                              hipStream_t stream)
{
    const float* he_feat = (const float*)d_in[0];
    float* out = (float*)d_out;

    EdgeIdx Esrc, Edst;
    for (int g = 0; g < 3; ++g) {
        Esrc.p[g] = (const int*)d_in[34 + 2 * g];
        Edst.p[g] = (const int*)d_in[35 + 2 * g];
    }

    char* base = (char*)d_ws;
    size_t off = 0;
    auto alloc = [&](size_t bytes) -> void* {
        void* r = (void*)(base + off);
        off = (off + bytes + 255) & ~(size_t)255;
        return r;
    };
    // ---- persistent small region (~2.4 MB) ----
    float* W12f = (float*)alloc(IN_F * E_DIM * 4);
    float* b12 = (float*)alloc(E_DIM * 4);
    float* Bkvf = (float*)alloc(E_DIM * R_STRIDE * 4);
    bf16* WRt_hi = (bf16*)alloc(256 * KP_HE * 2);
    bf16* WRt_lo = (bf16*)alloc(256 * KP_HE * 2);
    float* bR = (float*)alloc(R_STRIDE * 4);
    bf16* Wct_hi = (bf16*)alloc(256 * T_STRIDE * 2);
    bf16* Wct_lo = (bf16*)alloc(256 * T_STRIDE * 2);
    float* b_comp = (float*)alloc(256 * 4);
    bf16* Wm2t_hi = (bf16*)alloc(128 * 256 * 2);
    bf16* Wm2t_lo = (bf16*)alloc(128 * 256 * 2);
    float* q_t = (float*)alloc(N_NODES * Q_DIM * 4);
    int* bincursor = (int*)alloc(3 * NBIN * 4);
    int2* rows2 = (int2*)alloc((size_t)3 * N_HE * 8);
    // ---- big buffers with lifetime overlays (~99.5 MB total) ----
    size_t T_start = off;
    float* T = (float*)alloc((size_t)M_PAD * T_STRIDE * 4);    // 38.4 MB [attn -> mlp1]
    size_t R_start = off;
    float* R = (float*)alloc((size_t)N_HE * R_STRIDE * 4);     // 43.2 MB [R-gemm -> attn]
    int* ebuf = (int*)alloc((size_t)3 * NBIN * BINCAP * 4);    // 15.4 MB [bin_csr -> attn]
    // overlays:
    unsigned* binbuf = (unsigned*)(base + T_start);             // 15.4 MB [scatter -> csr], dead before attn writes T
    float* h1 = (float*)(base + R_start);                       // 51.2 MB [mlp1 -> mlp2], over dead R+ebuf

    // ---- fused prep (also zeroes bincursor; must precede bin_scatter) ----
    PrepArgs P;
    P.w1w = (const float*)d_in[4]; P.w1b = (const float*)d_in[5];
    P.w2w = (const float*)d_in[6]; P.w2b = (const float*)d_in[7];
    P.W12f = W12f; P.b12 = b12;
    for (int g = 0; g < 3; ++g) {
        P.w6[g] = (const float*)d_in[18 + 4 * g];
        P.b6[g] = (const float*)d_in[19 + 4 * g];
        P.w7[g] = (const float*)d_in[20 + 4 * g];
        P.b7[g] = (const float*)d_in[21 + 4 * g];
        P.feat[g] = (const float*)d_in[1 + g];
        P.w5[g] = (const float*)d_in[12 + 2 * g];
        P.b5[g] = (const float*)d_in[13 + 2 * g];
    }
    P.Bkvf = Bkvf;
    P.mlp1w = (const float*)d_in[30]; P.mlp1b = (const float*)d_in[31];
    P.Wct_hi = Wct_hi; P.Wct_lo = Wct_lo; P.b_comp = b_comp;
    P.mlp2w = (const float*)d_in[32];
    P.Wm2t_hi = Wm2t_hi; P.Wm2t_lo = Wm2t_lo;
    P.q_t = q_t;
    P.bincursor = bincursor;
    prep_fused_kernel<<<650 + N_NODES + 2, 256, 0, stream>>>(P);

    // ---- binned CSR build + W_R compose ----
    {
        dim3 grid((E_EDGES + ECHUNK - 1) / ECHUNK, 3);
        bin_scatter_kernel<<<grid, 256, 0, stream>>>(Esrc, Edst, bincursor, binbuf);
        csr_wr_fused_kernel<<<3 * NBIN + 256, 256, 0, stream>>>(
            binbuf, bincursor, rows2, ebuf, W12f, b12, Bkvf, WRt_hi, WRt_lo, bR);
    }

    const int MB = M_PAD / 128; // 391
    const float* mlp2b = (const float*)d_in[33];
    // R = he_feat @ W_R + bR  (guarded: he_feat is [50000][200] unpadded)
    mfma_gemm_kernel<true, true, false><<<dim3(MB, 4), 256, 0, stream>>>(
        he_feat, IN_F, KP_HE, N_HE, WRt_hi, WRt_lo, bR, R, N_HE, R_STRIDE, R_STRIDE);
    // attention -> T f32 [M_PAD][192]  (overwrites binbuf: dead)
    attn_kernel<<<(3 * N_HE) / 4, 256, 0, stream>>>(R, q_t, rows2, ebuf, T);
    // h1 = relu(T @ W_comp + b_comp)  (overwrites R/ebuf: dead)
    mfma_gemm_kernel<false, true, true><<<dim3(MB, 4), 256, 0, stream>>>(
        T, T_STRIDE, T_STRIDE, M_PAD, Wct_hi, Wct_lo, b_comp, h1, M_PAD, 256, 256);
    // out = relu(h1 @ mlp2w + mlp2b)
    mfma_gemm_kernel<false, true, true><<<dim3(MB, 2), 256, 0, stream>>>(
        h1, 256, 256, M_PAD, Wm2t_hi, Wm2t_lo, mlp2b, out, N_HE, E_DIM, E_DIM);
}

// Round 12
// 278.760 us; speedup vs baseline: 1.4398x; 1.0350x over previous
//
#include <hip/hip_runtime.h>
#include <hip/hip_bf16.h>

typedef __hip_bfloat16 bf16;
typedef float f32x4 __attribute__((ext_vector_type(4)));
typedef short bf16x8s __attribute__((ext_vector_type(8)));
typedef unsigned short u16x8 __attribute__((ext_vector_type(8)));

constexpr int N_HE = 50000;
constexpr int M_PAD = 50048;           // 391 * 128
constexpr int E_EDGES = 1200000;
constexpr int IN_F = 200;
constexpr int KP_HE = 224;             // 200 padded to x32
constexpr int HE_DIM = 512;
constexpr int E_DIM = 128;
constexpr int Q_DIM = 64;
constexpr float SL2E = 0.125f * 1.44269504088896f; // SCALE * log2(e), folded into W_R/bR
constexpr int N_NODES = 1489;
constexpr int R_STRIDE = 216;          // 3 x 72 (64 r + 1 c + 7 pad)
constexpr int T_STRIDE = 192;          // 3 x 64
constexpr int LDSD = 40;               // LDS row stride (bf16) for GEMM staging
constexpr int NBIN = 98;               // ceil(50000/512) bins per group
constexpr int BIN_SHIFT = 9;           // 512 hyperedges per bin
constexpr int ECHUNK = 4096;           // edges per scatter block
constexpr int NCHUNK = (E_EDGES + ECHUNK - 1) / ECHUNK; // 293
constexpr int BINCAP = 13056;          // mean 12288 + 7 sigma, clamp-guarded
constexpr int SCAT_BLKS = 3 * NCHUNK;  // 879
constexpr int PREP_BLKS = 650 + N_NODES; // 2139

struct EdgeIdx { const int* p[3]; };

__device__ __forceinline__ void split2(float v, bf16& h, bf16& l)
{
    bf16 hb = __float2bfloat16(v);
    h = hb;
    l = __float2bfloat16(v - __bfloat162float(hb));
}
__device__ __forceinline__ void split2u(float v, unsigned short& h, unsigned short& l)
{
    bf16 hb = __float2bfloat16(v);
    bf16 lb = __float2bfloat16(v - __bfloat162float(hb));
    h = *reinterpret_cast<unsigned short*>(&hb);
    l = *reinterpret_cast<unsigned short*>(&lb);
}
__device__ __forceinline__ float exp2_fast(float x)
{
    float r;
    asm("v_exp_f32 %0, %1" : "=v"(r) : "v"(x));
    return r;
}
// 16-lane (DPP-row) sum reduction, pure VALU: xor1, xor2 via quad_perm;
// quad-pair via row_half_mirror; half-pair via row_mirror. All lanes get the sum.
__device__ __forceinline__ float red16(float x)
{
    x += __int_as_float(__builtin_amdgcn_update_dpp(0, __float_as_int(x), 0xB1, 0xF, 0xF, true));
    x += __int_as_float(__builtin_amdgcn_update_dpp(0, __float_as_int(x), 0x4E, 0xF, 0xF, true));
    x += __int_as_float(__builtin_amdgcn_update_dpp(0, __float_as_int(x), 0x141, 0xF, 0xF, true));
    x += __int_as_float(__builtin_amdgcn_update_dpp(0, __float_as_int(x), 0x140, 0xF, 0xF, true));
    return x;
}

// ================= fused: bin_scatter (879 blocks) + prep (2139 blocks) =================
struct PrepArgs {
    const float *w1w, *w1b, *w2w, *w2b;
    float *W12f, *b12;
    const float *w6[3], *b6[3];
    float *Bkvf;
    const float *w7[3], *b7[3];
    const float *mlp1w, *mlp1b;
    bf16 *Wct_hi, *Wct_lo;
    float *b_comp;
    const float *mlp2w;
    bf16 *Wm2t_hi, *Wm2t_lo;
    const float *feat[3], *w5[3], *b5[3];
    float *q_t;
};

__global__ __launch_bounds__(256) void scatter_prep_fused_kernel(
    EdgeIdx S, EdgeIdx D, int* __restrict__ bincursor, unsigned* __restrict__ binbuf,
    PrepArgs P)
{
    __shared__ unsigned stage[ECHUNK];
    __shared__ int hist4[4][NBIN];
    __shared__ int hist[NBIN], off[NBIN], cur[NBIN], gbase[NBIN];
    int bid = blockIdx.x, tid = threadIdx.x;
    if (bid < SCAT_BLKS) {
        // ---------------- bin_scatter ----------------
        int g = bid / NCHUNK, chunk = bid - g * NCHUNK;
        const int* src = S.p[g];
        const int* dst = D.p[g];
        int lane = tid & 63, w = tid >> 6;
        for (int b = tid; b < 4 * NBIN; b += 256) (&hist4[0][0])[b] = 0;
        __syncthreads();
        int base = chunk * ECHUNK;
        int s[ECHUNK / 256], d[ECHUNK / 256];
#pragma unroll
        for (int k = 0; k < ECHUNK / 256; ++k) {
            int i = base + k * 256 + tid;
            if (i < E_EDGES) {
                s[k] = src[i];
                d[k] = dst[i];
                atomicAdd(&hist4[w][s[k] >> BIN_SHIFT], 1);
            } else s[k] = -1;
        }
        __syncthreads();
        if (w == 0) {
            int i1 = 64 + lane;
            int v0 = 0, v1 = 0;
            if (lane < NBIN) v0 = hist4[0][lane] + hist4[1][lane] + hist4[2][lane] + hist4[3][lane];
            if (i1 < NBIN) v1 = hist4[0][i1] + hist4[1][i1] + hist4[2][i1] + hist4[3][i1];
            int x0 = v0, x1 = v1;
#pragma unroll
            for (int o = 1; o < 64; o <<= 1) {
                int t0 = __shfl_up(x0, o, 64);
                int t1 = __shfl_up(x1, o, 64);
                if (lane >= o) { x0 += t0; x1 += t1; }
            }
            int tot0 = __shfl(x0, 63, 64);
            if (lane < NBIN) { hist[lane] = v0; off[lane] = x0 - v0; cur[lane] = x0 - v0; }
            if (i1 < NBIN) { hist[i1] = v1; off[i1] = tot0 + x1 - v1; cur[i1] = tot0 + x1 - v1; }
        }
        __syncthreads();
        if (tid < NBIN) gbase[tid] = hist[tid] ? atomicAdd(&bincursor[g * NBIN + tid], hist[tid]) : 0;
        __syncthreads();
#pragma unroll
        for (int k = 0; k < ECHUNK / 256; ++k) {
            if (s[k] >= 0) {
                int bin = s[k] >> BIN_SHIFT;
                int pos = atomicAdd(&cur[bin], 1);
                stage[pos] = ((unsigned)(s[k] & 511) << 10) | (unsigned)d[k];
            }
        }
        __syncthreads();
        size_t gslot = (size_t)g * NBIN * BINCAP;
        for (int b = w; b < NBIN; b += 4) {
            int len = hist[b];
            if (!len) continue;
            int gb = gbase[b];
            int avail = BINCAP - gb;
            if (avail <= 0) continue;
            if (len > avail) len = avail;
            int lo = off[b];
            size_t obase = gslot + (size_t)b * BINCAP + gb;
            for (int j = lane; j < len; j += 64)
                binbuf[obase + j] = stage[lo + j];
        }
        return;
    }
    // ---------------- prep (reuses `stage` LDS as float scratch) ----------------
    float* sh = (float*)stage;
    int pb = bid - SCAT_BLKS;
    if (pb < 201) {
        int row = pb;
        int col = tid & 127, ks = tid >> 7;
        const float* a = (row < IN_F) ? (P.w1w + (size_t)row * HE_DIM) : P.w1b;
        float s = 0.f;
#pragma unroll 4
        for (int k = ks; k < HE_DIM; k += 2)
            s = fmaf(a[k], P.w2w[k * E_DIM + col], s);
        sh[ks * 128 + col] = s;
        __syncthreads();
        if (ks == 0) {
            float v = sh[col] + sh[128 + col];
            if (row < IN_F) P.W12f[row * E_DIM + col] = v;
            else P.b12[col] = v + P.w2b[col];
        }
    } else if (pb < 329) {
        int k = pb - 201;
        int c = tid;
        if (c < R_STRIDE) {
            int g = c / 72, j = c - g * 72;
            float v = 0.f;
            if (j < 64) v = P.w6[g][j * E_DIM + k];
            else if (j == 64) v = P.b6[g][k];
            P.Bkvf[k * R_STRIDE + c] = v;
        }
    } else if (pb < 522) {
        int row = pb - 329;
        int n = tid;
        if (row < 192) {
            int g = row >> 6, i = row & 63;
            const float* w7 = P.w7[g];
            float s = 0.f;
#pragma unroll 4
            for (int k = 0; k < 128; ++k)
                s = fmaf(w7[i * 128 + k], P.mlp1w[(size_t)(g * 128 + k) * 256 + n], s);
            bf16 h, l; split2(s, h, l);
            P.Wct_hi[n * T_STRIDE + row] = h;
            P.Wct_lo[n * T_STRIDE + row] = l;
        } else {
            float s = P.mlp1b[n];
            for (int g = 0; g < 3; ++g)
#pragma unroll 4
                for (int k = 0; k < 128; ++k)
                    s = fmaf(P.b7[g][k], P.mlp1w[(size_t)(g * 128 + k) * 256 + n], s);
            P.b_comp[n] = s;
        }
    } else if (pb < 650) {
        int n = pb - 522;
        int k = tid;
        float v = P.mlp2w[(size_t)k * 128 + n];
        bf16 h, l; split2(v, h, l);
        P.Wm2t_hi[n * 256 + k] = h;
        P.Wm2t_lo[n * 256 + k] = l;
    } else {
        int b = pb - 650; // 0..1488
        int g = (b < 167) ? 0 : (b < 1048 ? 1 : 2);
        int row = b - (g == 0 ? 0 : (g == 1 ? 167 : 1048));
        int Dt = (g == 0) ? 167 : (g == 1 ? 881 : 441);
        const float* feat = P.feat[g] + (size_t)row * Dt;
        const float* w5 = P.w5[g];
        int col = tid & 63, ks = tid >> 6;
        float s = 0.f;
#pragma unroll 4
        for (int k = ks; k < Dt; k += 4)
            s = fmaf(feat[k], w5[k * Q_DIM + col], s);
        sh[ks * 64 + col] = s;
        __syncthreads();
        if (ks == 0)
            P.q_t[(size_t)b * Q_DIM + col] =
                sh[col] + sh[64 + col] + sh[128 + col] + sh[192 + col] + P.b5[g][col];
    }
}

// ---------------- fused: bin_csr (294 blocks) + compose_wr (256 blocks) ----------------
__global__ __launch_bounds__(256) void csr_wr_fused_kernel(
    const unsigned* __restrict__ binbuf, const int* __restrict__ bincursor,
    int2* __restrict__ rows2_all, int* __restrict__ ebuf,
    const float* __restrict__ W12f, const float* __restrict__ b12,
    const float* __restrict__ Bkvf,
    bf16* __restrict__ WRt_hi, bf16* __restrict__ WRt_lo, float* __restrict__ bR)
{
    __shared__ int hist[512], cur[512], cs[8];
    __shared__ float fcol[128];
    int bid = blockIdx.x, tid = threadIdx.x;
    if (bid < 3 * NBIN) {
        int g = bid / NBIN, b = bid - g * NBIN;
        int cnt = min(bincursor[g * NBIN + b], BINCAP);
        size_t sbase = ((size_t)g * NBIN + b) * BINCAP;
        int h0 = b << BIN_SHIFT;
        int hN = min(512, N_HE - h0);
        int ebase_rel = b * BINCAP;
        int2* rows2 = rows2_all + g * N_HE;
        int lane = tid & 63, w = tid >> 6;
        hist[tid] = 0; hist[tid + 256] = 0;
        __syncthreads();
        for (int i = tid; i < cnt; i += 256)
            atomicAdd(&hist[binbuf[sbase + i] >> 10], 1);
        __syncthreads();
#pragma unroll
        for (int c2 = 0; c2 < 2; ++c2) {
            int c = w * 2 + c2, idx = c * 64 + lane;
            int v = hist[idx], x = v;
#pragma unroll
            for (int o = 1; o < 64; o <<= 1) {
                int t = __shfl_up(x, o, 64);
                if (lane >= o) x += t;
            }
            cur[idx] = x - v;
            if (lane == 63) cs[c] = x;
        }
        __syncthreads();
        if (tid == 0) {
            int run = 0;
#pragma unroll
            for (int c = 0; c < 8; ++c) { int t = cs[c]; cs[c] = run; run += t; }
        }
        __syncthreads();
#pragma unroll
        for (int c2 = 0; c2 < 2; ++c2) {
            int c = w * 2 + c2, idx = c * 64 + lane;
            int e = cur[idx] + cs[c];
            cur[idx] = e;
            if (idx < hN) rows2[h0 + idx] = make_int2(ebase_rel + e, ebase_rel + e + hist[idx]);
        }
        __syncthreads();
        for (int i = tid; i < cnt; i += 256) {
            unsigned p = binbuf[sbase + i];
            int pos = atomicAdd(&cur[p >> 10], 1);
            ebuf[sbase + pos] = (int)((p & 1023u) << 8); // byte offset into q_t rows (256 B/row)
        }
    } else {
        // compose W_R^T hi/lo [256][224] = (W12 @ Bkv)^T * SL2E ; bR = b12 @ Bkv * SL2E
        int c = bid - 3 * NBIN;  // 0..255
        const bf16 z = __float2bfloat16(0.f);
        if (c >= R_STRIDE) {
            if (tid < KP_HE) { WRt_hi[c * KP_HE + tid] = z; WRt_lo[c * KP_HE + tid] = z; }
            return;
        }
        if (tid < 128) fcol[tid] = Bkvf[tid * R_STRIDE + c];
        __syncthreads();
        if (tid < IN_F) {
            const float* wrow = W12f + (size_t)tid * E_DIM;
            float s = 0.f;
#pragma unroll 4
            for (int k = 0; k < 128; ++k) s = fmaf(wrow[k], fcol[k], s);
            bf16 h, l; split2(s * SL2E, h, l);
            WRt_hi[c * KP_HE + tid] = h;
            WRt_lo[c * KP_HE + tid] = l;
        } else if (tid < KP_HE) {
            WRt_hi[c * KP_HE + tid] = z;
            WRt_lo[c * KP_HE + tid] = z;
        } else if (tid == KP_HE) {
            float s = 0.f;
            for (int k = 0; k < 128; ++k) s = fmaf(b12[k], fcol[k], s);
            bR[c] = s * SL2E;
        }
    }
}

// ---------------- split-precision MFMA GEMM, f32 A (split in staging), f32 C ----------------
template <bool GUARD, bool BIAS, bool RELU>
__global__ __launch_bounds__(256) void mfma_gemm_kernel(
    const float* __restrict__ A, int lda, int Kp, int Mvalid,
    const bf16* __restrict__ Bthg, const bf16* __restrict__ Btlg,
    const float* __restrict__ bias,
    float* __restrict__ C, int M, int N, int ldc)
{
    __shared__ bf16 Ah[128 * LDSD], Al[128 * LDSD], Bh[64 * LDSD], Bl[64 * LDSD];
    const int tid = threadIdx.x;
    const int bm = blockIdx.x * 128, bn = blockIdx.y * 64;
    const int lane = tid & 63, w = tid >> 6;
    const int kgrp = lane >> 4, lr = lane & 15;
    const int arow = tid >> 1, ahalf = (tid & 1) * 16;
    const int brow = tid >> 2, bq = (tid & 3) * 8;
    f32x4 acc[2][4] = {};

    for (int k0 = 0; k0 < Kp; k0 += 32) {
        {
            int row = bm + arow, kb = k0 + ahalf;
            float va[16];
            if (!GUARD || (row < Mvalid && kb + 16 <= lda)) {
                const float* ap = A + (size_t)row * lda + kb;
                *(float4*)&va[0]  = *(const float4*)ap;
                *(float4*)&va[4]  = *(const float4*)(ap + 4);
                *(float4*)&va[8]  = *(const float4*)(ap + 8);
                *(float4*)&va[12] = *(const float4*)(ap + 12);
            } else {
#pragma unroll
                for (int j = 0; j < 16; ++j) {
                    int k = kb + j;
                    va[j] = (row < Mvalid && k < lda) ? A[(size_t)row * lda + k] : 0.f;
                }
            }
            u16x8 H0, H1, L0, L1;
#pragma unroll
            for (int j = 0; j < 8; ++j) {
                unsigned short h, l;
                split2u(va[j], h, l);       H0[j] = h; L0[j] = l;
                split2u(va[8 + j], h, l);   H1[j] = h; L1[j] = l;
            }
            *(u16x8*)&Ah[arow * LDSD + ahalf] = H0;
            *(u16x8*)&Ah[arow * LDSD + ahalf + 8] = H1;
            *(u16x8*)&Al[arow * LDSD + ahalf] = L0;
            *(u16x8*)&Al[arow * LDSD + ahalf + 8] = L1;
            const size_t bbase = (size_t)(bn + brow) * Kp + k0 + bq;
            uint4 w0 = *(const uint4*)(Bthg + bbase);
            uint4 w1 = *(const uint4*)(Btlg + bbase);
            *(uint4*)&Bh[brow * LDSD + bq] = w0;
            *(uint4*)&Bl[brow * LDSD + bq] = w1;
        }
        __syncthreads();
        bf16x8s afh[2], afl[2], bfh[4], bfl[4];
#pragma unroll
        for (int mi = 0; mi < 2; ++mi) {
            int r = w * 32 + mi * 16 + lr;
            afh[mi] = *(const bf16x8s*)&Ah[r * LDSD + kgrp * 8];
            afl[mi] = *(const bf16x8s*)&Al[r * LDSD + kgrp * 8];
        }
#pragma unroll
        for (int ni = 0; ni < 4; ++ni) {
            int r = ni * 16 + lr;
            bfh[ni] = *(const bf16x8s*)&Bh[r * LDSD + kgrp * 8];
            bfl[ni] = *(const bf16x8s*)&Bl[r * LDSD + kgrp * 8];
        }
#pragma unroll
        for (int mi = 0; mi < 2; ++mi)
#pragma unroll
            for (int ni = 0; ni < 4; ++ni) {
                acc[mi][ni] = __builtin_amdgcn_mfma_f32_16x16x32_bf16(afh[mi], bfh[ni], acc[mi][ni], 0, 0, 0);
                acc[mi][ni] = __builtin_amdgcn_mfma_f32_16x16x32_bf16(afl[mi], bfh[ni], acc[mi][ni], 0, 0, 0);
                acc[mi][ni] = __builtin_amdgcn_mfma_f32_16x16x32_bf16(afh[mi], bfl[ni], acc[mi][ni], 0, 0, 0);
            }
        __syncthreads();
    }

    // epilogue: D col = lane&15, row = (lane>>4)*4 + reg  [m89-verified layout]
#pragma unroll
    for (int mi = 0; mi < 2; ++mi) {
#pragma unroll
        for (int ni = 0; ni < 4; ++ni) {
            int col = bn + ni * 16 + lr;
            float bv = 0.f;
            if (BIAS) bv = (col < N) ? bias[col] : 0.f;
            int row0 = bm + w * 32 + mi * 16 + kgrp * 4;
#pragma unroll
            for (int r = 0; r < 4; ++r) {
                float v = acc[mi][ni][r] + bv;
                if (RELU) v = fmaxf(v, 0.f);
                int row = row0 + r;
                if (row < M && col < N) C[(size_t)row * ldc + col] = v;
            }
        }
    }
}

// ---------------- attention: fixed-max, log2-domain, DPP reduce ----------------
__global__ __launch_bounds__(256) void attn_kernel(
    const float* __restrict__ R,        // [N_HE][216], scores pre-scaled by SL2E
    const float* __restrict__ q_t,      // [1489][64]
    const int2* __restrict__ rows2_all, // [3][N_HE] group-relative (start,end)
    const int* __restrict__ ebuf_all,   // [3][NBIN*BINCAP], holds d<<8 byte offsets
    float* __restrict__ T)              // [M_PAD][192] f32
{
    int wid = blockIdx.x * 4 + (threadIdx.x >> 6);
    int lane = threadIdx.x & 63;
    int g = wid / N_HE;
    int h = wid - g * N_HE;
    const int toff_tab[3] = {0, 167, 1048};
    const char* qb = (const char*)(q_t + (size_t)toff_tab[g] * Q_DIM);
    const int* ebuf = ebuf_all + (size_t)g * NBIN * BINCAP;
    int2 se = rows2_all[g * N_HE + h];
    int start = se.x, end = se.y;

    int sub = lane >> 4, sl = lane & 15;
    const float* Rrow = R + (size_t)h * R_STRIDE + g * 72;
    float4 r4 = *reinterpret_cast<const float4*>(Rrow + sl * 4);
    float ch = Rrow[64];
    int slo = sl * 16;

    float denom = 0.f;
    float acc0 = 0.f, acc1 = 0.f, acc2 = 0.f, acc3 = 0.f;

    for (int i0 = start + sub * 2; i0 < end; i0 += 8) {
        bool ok1 = (i0 + 1) < end;
        int o0 = ebuf[i0];
        int o1 = ebuf[ok1 ? i0 + 1 : i0];
        float4 t0 = *reinterpret_cast<const float4*>(qb + o0 + slo);
        float4 t1 = *reinterpret_cast<const float4*>(qb + o1 + slo);
        float p0 = t0.x * r4.x;
        p0 = fmaf(t0.y, r4.y, p0); p0 = fmaf(t0.z, r4.z, p0); p0 = fmaf(t0.w, r4.w, p0);
        float p1 = t1.x * r4.x;
        p1 = fmaf(t1.y, r4.y, p1); p1 = fmaf(t1.z, r4.z, p1); p1 = fmaf(t1.w, r4.w, p1);
        p0 = red16(p0);           // pure-VALU DPP row reduce (16 lanes)
        p1 = red16(p1);
        float s0 = p0 + ch; s0 = fmaxf(s0, 0.01f * s0);   // leaky_relu (scores pre-scaled)
        float s1 = p1 + ch; s1 = fmaxf(s1, 0.01f * s1);
        float w0 = exp2_fast(s0);
        float w1 = ok1 ? exp2_fast(s1) : 0.f;
        denom += w0 + w1;
        acc0 = fmaf(w0, t0.x, fmaf(w1, t1.x, acc0));
        acc1 = fmaf(w0, t0.y, fmaf(w1, t1.y, acc1));
        acc2 = fmaf(w0, t0.z, fmaf(w1, t1.z, acc2));
        acc3 = fmaf(w0, t0.w, fmaf(w1, t1.w, acc3));
    }

    // sum across the 4 subgroups (cross-row: keep shfl, once per wave)
    denom += __shfl_xor(denom, 16, 64); denom += __shfl_xor(denom, 32, 64);
    acc0 += __shfl_xor(acc0, 16, 64); acc0 += __shfl_xor(acc0, 32, 64);
    acc1 += __shfl_xor(acc1, 16, 64); acc1 += __shfl_xor(acc1, 32, 64);
    acc2 += __shfl_xor(acc2, 16, 64); acc2 += __shfl_xor(acc2, 32, 64);
    acc3 += __shfl_xor(acc3, 16, 64); acc3 += __shfl_xor(acc3, 32, 64);
    if (sub == 0) {
        float rden = 1.f / fmaxf(denom, 1e-20f);
        float4 o = {acc0 * rden, acc1 * rden, acc2 * rden, acc3 * rden};
        *reinterpret_cast<float4*>(T + (size_t)h * T_STRIDE + g * 64 + sl * 4) = o;
    }
}

// ---------------- launch ----------------
extern "C" void kernel_launch(void* const* d_in, const int* in_sizes, int n_in,
                              void* d_out, int out_size, void* d_ws, size_t ws_size,
                              hipStream_t stream)
{
    const float* he_feat = (const float*)d_in[0];
    float* out = (float*)d_out;

    EdgeIdx Esrc, Edst;
    for (int g = 0; g < 3; ++g) {
        Esrc.p[g] = (const int*)d_in[34 + 2 * g];
        Edst.p[g] = (const int*)d_in[35 + 2 * g];
    }

    char* base = (char*)d_ws;
    size_t off = 0;
    auto alloc = [&](size_t bytes) -> void* {
        void* r = (void*)(base + off);
        off = (off + bytes + 255) & ~(size_t)255;
        return r;
    };
    // ---- persistent small region (~2.4 MB) ----
    float* W12f = (float*)alloc(IN_F * E_DIM * 4);
    float* b12 = (float*)alloc(E_DIM * 4);
    float* Bkvf = (float*)alloc(E_DIM * R_STRIDE * 4);
    bf16* WRt_hi = (bf16*)alloc(256 * KP_HE * 2);
    bf16* WRt_lo = (bf16*)alloc(256 * KP_HE * 2);
    float* bR = (float*)alloc(R_STRIDE * 4);
    bf16* Wct_hi = (bf16*)alloc(256 * T_STRIDE * 2);
    bf16* Wct_lo = (bf16*)alloc(256 * T_STRIDE * 2);
    float* b_comp = (float*)alloc(256 * 4);
    bf16* Wm2t_hi = (bf16*)alloc(128 * 256 * 2);
    bf16* Wm2t_lo = (bf16*)alloc(128 * 256 * 2);
    float* q_t = (float*)alloc(N_NODES * Q_DIM * 4);
    int* bincursor = (int*)alloc(3 * NBIN * 4);
    int2* rows2 = (int2*)alloc((size_t)3 * N_HE * 8);
    // ---- big buffers with lifetime overlays (~99.5 MB total) ----
    size_t T_start = off;
    float* T = (float*)alloc((size_t)M_PAD * T_STRIDE * 4);    // 38.4 MB [attn -> mlp1]
    size_t R_start = off;
    float* R = (float*)alloc((size_t)N_HE * R_STRIDE * 4);     // 43.2 MB [R-gemm -> attn]
    int* ebuf = (int*)alloc((size_t)3 * NBIN * BINCAP * 4);    // 15.4 MB [bin_csr -> attn]
    // overlays:
    unsigned* binbuf = (unsigned*)(base + T_start);             // 15.4 MB [scatter -> csr], dead before attn writes T
    float* h1 = (float*)(base + R_start);                       // 51.2 MB [mlp1 -> mlp2], over dead R+ebuf

    hipMemsetAsync(bincursor, 0, 3 * NBIN * 4, stream);

    // ---- fused scatter + prep (mutually independent block ranges) ----
    PrepArgs P;
    P.w1w = (const float*)d_in[4]; P.w1b = (const float*)d_in[5];
    P.w2w = (const float*)d_in[6]; P.w2b = (const float*)d_in[7];
    P.W12f = W12f; P.b12 = b12;
    for (int g = 0; g < 3; ++g) {
        P.w6[g] = (const float*)d_in[18 + 4 * g];
        P.b6[g] = (const float*)d_in[19 + 4 * g];
        P.w7[g] = (const float*)d_in[20 + 4 * g];
        P.b7[g] = (const float*)d_in[21 + 4 * g];
        P.feat[g] = (const float*)d_in[1 + g];
        P.w5[g] = (const float*)d_in[12 + 2 * g];
        P.b5[g] = (const float*)d_in[13 + 2 * g];
    }
    P.Bkvf = Bkvf;
    P.mlp1w = (const float*)d_in[30]; P.mlp1b = (const float*)d_in[31];
    P.Wct_hi = Wct_hi; P.Wct_lo = Wct_lo; P.b_comp = b_comp;
    P.mlp2w = (const float*)d_in[32];
    P.Wm2t_hi = Wm2t_hi; P.Wm2t_lo = Wm2t_lo;
    P.q_t = q_t;
    scatter_prep_fused_kernel<<<SCAT_BLKS + PREP_BLKS, 256, 0, stream>>>(
        Esrc, Edst, bincursor, binbuf, P);

    // ---- binned CSR finalize + W_R compose ----
    csr_wr_fused_kernel<<<3 * NBIN + 256, 256, 0, stream>>>(
        binbuf, bincursor, rows2, ebuf, W12f, b12, Bkvf, WRt_hi, WRt_lo, bR);

    const int MB = M_PAD / 128; // 391
    const float* mlp2b = (const float*)d_in[33];
    // R = he_feat @ W_R + bR  (guarded: he_feat is [50000][200] unpadded)
    mfma_gemm_kernel<true, true, false><<<dim3(MB, 4), 256, 0, stream>>>(
        he_feat, IN_F, KP_HE, N_HE, WRt_hi, WRt_lo, bR, R, N_HE, R_STRIDE, R_STRIDE);
    // attention -> T f32 [M_PAD][192]  (overwrites binbuf: dead)
    attn_kernel<<<(3 * N_HE) / 4, 256, 0, stream>>>(R, q_t, rows2, ebuf, T);
    // h1 = relu(T @ W_comp + b_comp)  (overwrites R/ebuf: dead)
    mfma_gemm_kernel<false, true, true><<<dim3(MB, 4), 256, 0, stream>>>(
        T, T_STRIDE, T_STRIDE, M_PAD, Wct_hi, Wct_lo, b_comp, h1, M_PAD, 256, 256);
    // out = relu(h1 @ mlp2w + mlp2b)
    mfma_gemm_kernel<false, true, true><<<dim3(MB, 2), 256, 0, stream>>>(
        h1, 256, 256, M_PAD, Wm2t_hi, Wm2t_lo, mlp2b, out, N_HE, E_DIM, E_DIM);
}

// Round 14
// 257.441 us; speedup vs baseline: 1.5590x; 1.0828x over previous
//
#include <hip/hip_runtime.h>
#include <hip/hip_bf16.h>

typedef __hip_bfloat16 bf16;
typedef float f32x4 __attribute__((ext_vector_type(4)));
typedef short bf16x8s __attribute__((ext_vector_type(8)));
typedef unsigned short u16x8 __attribute__((ext_vector_type(8)));

constexpr int N_HE = 50000;
constexpr int M_PAD = 50048;           // 391 * 128
constexpr int E_EDGES = 1200000;
constexpr int IN_F = 200;
constexpr int KP_HE = 224;             // 200 padded to x32
constexpr int HE_DIM = 512;
constexpr int E_DIM = 128;
constexpr int Q_DIM = 64;
constexpr float SL2E = 0.125f * 1.44269504088896f; // SCALE * log2(e), folded into W_R/bR
constexpr int N_NODES = 1489;
constexpr int R_STRIDE = 216;          // 3 x 72 (64 r + 1 c + 7 pad)
constexpr int T_STRIDE = 192;          // 3 x 64
constexpr int LDSD = 40;               // LDS row stride (bf16) for GEMM staging
constexpr int NBIN = 98;               // ceil(50000/512) bins per group
constexpr int BIN_SHIFT = 9;           // 512 hyperedges per bin
constexpr int ECHUNK = 4096;           // edges per scatter block
constexpr int NCHUNK = (E_EDGES + ECHUNK - 1) / ECHUNK; // 293
constexpr int BINCAP = 13056;          // mean 12288 + 7 sigma, clamp-guarded
constexpr int SCAT_BLKS = 3 * NCHUNK;  // 879
// prep block ranges (after SCAT_BLKS): WR compose 256, Wct 193, m2t 128, node_q 1489
constexpr int PREP_BLKS = 256 + 193 + 128 + N_NODES; // 2066
constexpr int MB = M_PAD / 128;        // 391

struct EdgeIdx { const int* p[3]; };

__device__ __forceinline__ void split2(float v, bf16& h, bf16& l)
{
    bf16 hb = __float2bfloat16(v);
    h = hb;
    l = __float2bfloat16(v - __bfloat162float(hb));
}
__device__ __forceinline__ void split2u(float v, unsigned short& h, unsigned short& l)
{
    bf16 hb = __float2bfloat16(v);
    bf16 lb = __float2bfloat16(v - __bfloat162float(hb));
    h = *reinterpret_cast<unsigned short*>(&hb);
    l = *reinterpret_cast<unsigned short*>(&lb);
}
__device__ __forceinline__ unsigned short bf16bits(float v)
{
    bf16 b = __float2bfloat16(v);
    return *reinterpret_cast<unsigned short*>(&b);
}
__device__ __forceinline__ float exp2_fast(float x)
{
    float r;
    asm("v_exp_f32 %0, %1" : "=v"(r) : "v"(x));
    return r;
}
// 16-lane (DPP-row) sum reduction, pure VALU. All lanes get the row sum.
__device__ __forceinline__ float red16(float x)
{
    x += __int_as_float(__builtin_amdgcn_update_dpp(0, __float_as_int(x), 0xB1, 0xF, 0xF, true));
    x += __int_as_float(__builtin_amdgcn_update_dpp(0, __float_as_int(x), 0x4E, 0xF, 0xF, true));
    x += __int_as_float(__builtin_amdgcn_update_dpp(0, __float_as_int(x), 0x141, 0xF, 0xF, true));
    x += __int_as_float(__builtin_amdgcn_update_dpp(0, __float_as_int(x), 0x140, 0xF, 0xF, true));
    return x;
}

// ================= fused: bin_scatter (879 blocks) + prep (2066 blocks) =================
struct PrepArgs {
    const float *w1w, *w1b, *w2w, *w2b;
    const float *w6[3], *b6[3];
    bf16 *WRt_hi, *WRt_lo;
    float *bR;
    const float *w7[3], *b7[3];
    const float *mlp1w, *mlp1b;
    bf16 *Wct_hi, *Wct_lo;
    float *b_comp;
    const float *mlp2w;
    bf16 *Wm2t_hi, *Wm2t_lo;
    const float *feat[3], *w5[3], *b5[3];
    float *q_t;
};

__global__ __launch_bounds__(256) void scatter_prep_fused_kernel(
    EdgeIdx S, EdgeIdx D, int* __restrict__ bincursor, unsigned* __restrict__ binbuf,
    PrepArgs P)
{
    __shared__ unsigned stage[ECHUNK];
    __shared__ int hist4[4][NBIN];
    __shared__ int hist[NBIN], off[NBIN], cur[NBIN], gbase[NBIN];
    int bid = blockIdx.x, tid = threadIdx.x;
    if (bid < SCAT_BLKS) {
        // ---------------- bin_scatter ----------------
        int g = bid / NCHUNK, chunk = bid - g * NCHUNK;
        const int* src = S.p[g];
        const int* dst = D.p[g];
        int lane = tid & 63, w = tid >> 6;
        for (int b = tid; b < 4 * NBIN; b += 256) (&hist4[0][0])[b] = 0;
        __syncthreads();
        int base = chunk * ECHUNK;
        int s[ECHUNK / 256], d[ECHUNK / 256];
#pragma unroll
        for (int k = 0; k < ECHUNK / 256; ++k) {
            int i = base + k * 256 + tid;
            if (i < E_EDGES) {
                s[k] = src[i];
                d[k] = dst[i];
                atomicAdd(&hist4[w][s[k] >> BIN_SHIFT], 1);
            } else s[k] = -1;
        }
        __syncthreads();
        if (w == 0) {
            int i1 = 64 + lane;
            int v0 = 0, v1 = 0;
            if (lane < NBIN) v0 = hist4[0][lane] + hist4[1][lane] + hist4[2][lane] + hist4[3][lane];
            if (i1 < NBIN) v1 = hist4[0][i1] + hist4[1][i1] + hist4[2][i1] + hist4[3][i1];
            int x0 = v0, x1 = v1;
#pragma unroll
            for (int o = 1; o < 64; o <<= 1) {
                int t0 = __shfl_up(x0, o, 64);
                int t1 = __shfl_up(x1, o, 64);
                if (lane >= o) { x0 += t0; x1 += t1; }
            }
            int tot0 = __shfl(x0, 63, 64);
            if (lane < NBIN) { hist[lane] = v0; off[lane] = x0 - v0; cur[lane] = x0 - v0; }
            if (i1 < NBIN) { hist[i1] = v1; off[i1] = tot0 + x1 - v1; cur[i1] = tot0 + x1 - v1; }
        }
        __syncthreads();
        if (tid < NBIN) gbase[tid] = hist[tid] ? atomicAdd(&bincursor[g * NBIN + tid], hist[tid]) : 0;
        __syncthreads();
#pragma unroll
        for (int k = 0; k < ECHUNK / 256; ++k) {
            if (s[k] >= 0) {
                int bin = s[k] >> BIN_SHIFT;
                int pos = atomicAdd(&cur[bin], 1);
                stage[pos] = ((unsigned)(s[k] & 511) << 10) | (unsigned)d[k];
            }
        }
        __syncthreads();
        size_t gslot = (size_t)g * NBIN * BINCAP;
        for (int b = w; b < NBIN; b += 4) {
            int len = hist[b];
            if (!len) continue;
            int gb = gbase[b];
            int avail = BINCAP - gb;
            if (avail <= 0) continue;
            if (len > avail) len = avail;
            int lo = off[b];
            size_t obase = gslot + (size_t)b * BINCAP + gb;
            for (int j = lane; j < len; j += 64)
                binbuf[obase + j] = stage[lo + j];
        }
        return;
    }
    // ---------------- prep (reuses `stage` LDS as float scratch) ----------------
    float* sh = (float*)stage;
    int pb = bid - SCAT_BLKS;
    if (pb < 256) {
        // W_R column c: bkv_c -> M2 = w2w@bkv_c -> W_R[:,c] = w1w@M2 (*SL2E); bR_c
        int c = pb;
        const bf16 z = __float2bfloat16(0.f);
        if (c >= R_STRIDE) {
            if (tid < KP_HE) { P.WRt_hi[c * KP_HE + tid] = z; P.WRt_lo[c * KP_HE + tid] = z; }
            return;
        }
        float* bkv = sh;          // [128]
        float* M2 = sh + 128;     // [512]
        float* psum = sh + 640;   // [32]
        int g = c / 72, j = c - g * 72;
        if (tid < 128) {
            float v = 0.f;
            if (j < 64) v = P.w6[g][j * E_DIM + tid];
            else if (j == 64) v = P.b6[g][tid];
            bkv[tid] = v;
        }
        __syncthreads();
        for (int h = tid; h < HE_DIM; h += 256) {
            const float* w2row = P.w2w + (size_t)h * E_DIM;
            float s = 0.f;
#pragma unroll 4
            for (int k = 0; k < 128; ++k) s = fmaf(w2row[k], bkv[k], s);
            M2[h] = s;
        }
        __syncthreads();
        if (tid < IN_F) {
            const float* w1row = P.w1w + (size_t)tid * HE_DIM;
            float s = 0.f;
#pragma unroll 4
            for (int h = 0; h < HE_DIM; ++h) s = fmaf(w1row[h], M2[h], s);
            bf16 hh, ll; split2(s * SL2E, hh, ll);
            P.WRt_hi[c * KP_HE + tid] = hh;
            P.WRt_lo[c * KP_HE + tid] = ll;
        } else if (tid < KP_HE) {
            P.WRt_hi[c * KP_HE + tid] = z;
            P.WRt_lo[c * KP_HE + tid] = z;
        } else {
            int l = tid - 224; // 0..31
            float s = 0.f;
#pragma unroll 4
            for (int h = l * 16; h < l * 16 + 16; ++h) s = fmaf(P.w1b[h], M2[h], s);
#pragma unroll
            for (int k = l * 4; k < l * 4 + 4; ++k) s = fmaf(P.w2b[k], bkv[k], s);
            psum[l] = s;
        }
        __syncthreads();
        if (tid == 224) {
            float s = 0.f;
#pragma unroll
            for (int l = 0; l < 32; ++l) s += psum[l];
            P.bR[c] = s * SL2E;
        }
    } else if (pb < 449) {
        // Wct^T hi/lo [256][192]; row 192 -> b_comp
        int row = pb - 256;
        int n = tid;
        if (row < 192) {
            int g = row >> 6, i = row & 63;
            const float* w7 = P.w7[g];
            float s = 0.f;
#pragma unroll 4
            for (int k = 0; k < 128; ++k)
                s = fmaf(w7[i * 128 + k], P.mlp1w[(size_t)(g * 128 + k) * 256 + n], s);
            bf16 h, l; split2(s, h, l);
            P.Wct_hi[n * T_STRIDE + row] = h;
            P.Wct_lo[n * T_STRIDE + row] = l;
        } else {
            float s = P.mlp1b[n];
            for (int g = 0; g < 3; ++g)
#pragma unroll 4
                for (int k = 0; k < 128; ++k)
                    s = fmaf(P.b7[g][k], P.mlp1w[(size_t)(g * 128 + k) * 256 + n], s);
            P.b_comp[n] = s;
        }
    } else if (pb < 577) {
        // mlp2w^T hi/lo [128][256]
        int n = pb - 449;
        int k = tid;
        float v = P.mlp2w[(size_t)k * 128 + n];
        bf16 h, l; split2(v, h, l);
        P.Wm2t_hi[n * 256 + k] = h;
        P.Wm2t_lo[n * 256 + k] = l;
    } else {
        // node q projection: one block per node row
        int b = pb - 577; // 0..1488
        int g = (b < 167) ? 0 : (b < 1048 ? 1 : 2);
        int row = b - (g == 0 ? 0 : (g == 1 ? 167 : 1048));
        int Dt = (g == 0) ? 167 : (g == 1 ? 881 : 441);
        const float* feat = P.feat[g] + (size_t)row * Dt;
        const float* w5 = P.w5[g];
        int col = tid & 63, ks = tid >> 6;
        float s = 0.f;
#pragma unroll 4
        for (int k = ks; k < Dt; k += 4)
            s = fmaf(feat[k], w5[k * Q_DIM + col], s);
        sh[ks * 64 + col] = s;
        __syncthreads();
        if (ks == 0)
            P.q_t[(size_t)b * Q_DIM + col] =
                sh[col] + sh[64 + col] + sh[128 + col] + sh[192 + col] + P.b5[g][col];
    }
}

// ---------------- f32-A split-3-pass MFMA GEMM body (device) ----------------
__device__ __forceinline__ void gemm_f32A_body(
    char* smem, int bx, int by, int tid,
    const float* __restrict__ A, int lda, int Kp, int Mvalid,
    const bf16* __restrict__ Bthg, const bf16* __restrict__ Btlg,
    const float* __restrict__ bias,
    float* __restrict__ C, int M, int N, int ldc)
{
    bf16* Ah = (bf16*)smem;
    bf16* Al = Ah + 128 * LDSD;
    bf16* Bh = Al + 128 * LDSD;
    bf16* Bl = Bh + 64 * LDSD;
    const int bm = bx * 128, bn = by * 64;
    const int lane = tid & 63, w = tid >> 6;
    const int kgrp = lane >> 4, lr = lane & 15;
    const int arow = tid >> 1, ahalf = (tid & 1) * 16;
    const int brow = tid >> 2, bq = (tid & 3) * 8;
    f32x4 acc[2][4] = {};

    for (int k0 = 0; k0 < Kp; k0 += 32) {
        {
            int row = bm + arow, kb = k0 + ahalf;
            float va[16];
            if (row < Mvalid && kb + 16 <= lda) {
                const float* ap = A + (size_t)row * lda + kb;
                *(float4*)&va[0]  = *(const float4*)ap;
                *(float4*)&va[4]  = *(const float4*)(ap + 4);
                *(float4*)&va[8]  = *(const float4*)(ap + 8);
                *(float4*)&va[12] = *(const float4*)(ap + 12);
            } else {
#pragma unroll
                for (int j = 0; j < 16; ++j) {
                    int k = kb + j;
                    va[j] = (row < Mvalid && k < lda) ? A[(size_t)row * lda + k] : 0.f;
                }
            }
            u16x8 H0, H1, L0, L1;
#pragma unroll
            for (int j = 0; j < 8; ++j) {
                unsigned short h, l;
                split2u(va[j], h, l);       H0[j] = h; L0[j] = l;
                split2u(va[8 + j], h, l);   H1[j] = h; L1[j] = l;
            }
            *(u16x8*)&Ah[arow * LDSD + ahalf] = H0;
            *(u16x8*)&Ah[arow * LDSD + ahalf + 8] = H1;
            *(u16x8*)&Al[arow * LDSD + ahalf] = L0;
            *(u16x8*)&Al[arow * LDSD + ahalf + 8] = L1;
            const size_t bbase = (size_t)(bn + brow) * Kp + k0 + bq;
            uint4 w0 = *(const uint4*)(Bthg + bbase);
            uint4 w1 = *(const uint4*)(Btlg + bbase);
            *(uint4*)&Bh[brow * LDSD + bq] = w0;
            *(uint4*)&Bl[brow * LDSD + bq] = w1;
        }
        __syncthreads();
        bf16x8s afh[2], afl[2], bfh[4], bfl[4];
#pragma unroll
        for (int mi = 0; mi < 2; ++mi) {
            int r = w * 32 + mi * 16 + lr;
            afh[mi] = *(const bf16x8s*)&Ah[r * LDSD + kgrp * 8];
            afl[mi] = *(const bf16x8s*)&Al[r * LDSD + kgrp * 8];
        }
#pragma unroll
        for (int ni = 0; ni < 4; ++ni) {
            int r = ni * 16 + lr;
            bfh[ni] = *(const bf16x8s*)&Bh[r * LDSD + kgrp * 8];
            bfl[ni] = *(const bf16x8s*)&Bl[r * LDSD + kgrp * 8];
        }
#pragma unroll
        for (int mi = 0; mi < 2; ++mi)
#pragma unroll
            for (int ni = 0; ni < 4; ++ni) {
                acc[mi][ni] = __builtin_amdgcn_mfma_f32_16x16x32_bf16(afh[mi], bfh[ni], acc[mi][ni], 0, 0, 0);
                acc[mi][ni] = __builtin_amdgcn_mfma_f32_16x16x32_bf16(afl[mi], bfh[ni], acc[mi][ni], 0, 0, 0);
                acc[mi][ni] = __builtin_amdgcn_mfma_f32_16x16x32_bf16(afh[mi], bfl[ni], acc[mi][ni], 0, 0, 0);
            }
        __syncthreads();
    }

#pragma unroll
    for (int mi = 0; mi < 2; ++mi) {
#pragma unroll
        for (int ni = 0; ni < 4; ++ni) {
            int col = bn + ni * 16 + lr;
            float bv = (col < N) ? bias[col] : 0.f;
            int row0 = bm + w * 32 + mi * 16 + kgrp * 4;
#pragma unroll
            for (int r = 0; r < 4; ++r) {
                float v = acc[mi][ni][r] + bv;
                int row = row0 + r;
                if (row < M && col < N) C[(size_t)row * ldc + col] = v;
            }
        }
    }
}

// ---------------- fused: bin_csr (294 blocks) + R-gemm (1564 blocks) ----------------
__global__ __launch_bounds__(256) void csr_gemm_fused_kernel(
    const unsigned* __restrict__ binbuf, const int* __restrict__ bincursor,
    int2* __restrict__ rows2_all, int* __restrict__ ebuf,
    const float* __restrict__ he_feat,
    const bf16* __restrict__ WRt_hi, const bf16* __restrict__ WRt_lo,
    const float* __restrict__ bR, float* __restrict__ R)
{
    __shared__ __attribute__((aligned(16))) char smem[30720];
    int bid = blockIdx.x, tid = threadIdx.x;
    if (bid < 3 * NBIN) {
        int* hist = (int*)smem;
        int* cur = hist + 512;
        int* cs = cur + 512;
        int g = bid / NBIN, b = bid - g * NBIN;
        int cnt = min(bincursor[g * NBIN + b], BINCAP);
        size_t sbase = ((size_t)g * NBIN + b) * BINCAP;
        int h0 = b << BIN_SHIFT;
        int hN = min(512, N_HE - h0);
        int ebase_rel = b * BINCAP;
        int2* rows2 = rows2_all + g * N_HE;
        int lane = tid & 63, w = tid >> 6;
        hist[tid] = 0; hist[tid + 256] = 0;
        __syncthreads();
        for (int i = tid; i < cnt; i += 256)
            atomicAdd(&hist[binbuf[sbase + i] >> 10], 1);
        __syncthreads();
#pragma unroll
        for (int c2 = 0; c2 < 2; ++c2) {
            int c = w * 2 + c2, idx = c * 64 + lane;
            int v = hist[idx], x = v;
#pragma unroll
            for (int o = 1; o < 64; o <<= 1) {
                int t = __shfl_up(x, o, 64);
                if (lane >= o) x += t;
            }
            cur[idx] = x - v;
            if (lane == 63) cs[c] = x;
        }
        __syncthreads();
        if (tid == 0) {
            int run = 0;
#pragma unroll
            for (int c = 0; c < 8; ++c) { int t = cs[c]; cs[c] = run; run += t; }
        }
        __syncthreads();
#pragma unroll
        for (int c2 = 0; c2 < 2; ++c2) {
            int c = w * 2 + c2, idx = c * 64 + lane;
            int e = cur[idx] + cs[c];
            cur[idx] = e;
            if (idx < hN) rows2[h0 + idx] = make_int2(ebase_rel + e, ebase_rel + e + hist[idx]);
        }
        __syncthreads();
        for (int i = tid; i < cnt; i += 256) {
            unsigned p = binbuf[sbase + i];
            int pos = atomicAdd(&cur[p >> 10], 1);
            ebuf[sbase + pos] = (int)((p & 1023u) << 8); // byte offset into q_t rows (256 B/row)
        }
    } else {
        int q = bid - 3 * NBIN;
        gemm_f32A_body(smem, q >> 2, q & 3, tid,
                       he_feat, IN_F, KP_HE, N_HE, WRt_hi, WRt_lo, bR,
                       R, N_HE, R_STRIDE, R_STRIDE);
    }
}

// ---------------- bf16-A 2-pass MFMA GEMM (A exact-as-stored) ----------------
template <bool OUT_BF16, bool MASK_ROW>
__global__ __launch_bounds__(256) void mfma_gemm_bf16A_kernel(
    const bf16* __restrict__ A, int lda, int Kp,
    const bf16* __restrict__ Bthg, const bf16* __restrict__ Btlg,
    const float* __restrict__ bias,
    float* __restrict__ Cf, bf16* __restrict__ Cb,
    int M, int N, int ldc)
{
    __shared__ bf16 Ah[128 * LDSD], Bh[64 * LDSD], Bl[64 * LDSD];
    const int tid = threadIdx.x;
    const int bm = blockIdx.x * 128, bn = blockIdx.y * 64;
    const int lane = tid & 63, w = tid >> 6;
    const int kgrp = lane >> 4, lr = lane & 15;
    const int arow = tid >> 1, ahalf = (tid & 1) * 16;
    const int brow = tid >> 2, bq = (tid & 3) * 8;
    f32x4 acc[2][4] = {};

    for (int k0 = 0; k0 < Kp; k0 += 32) {
        {
            const bf16* ap = A + (size_t)(bm + arow) * lda + k0 + ahalf;
            uint4 v0 = *(const uint4*)ap;
            uint4 v1 = *(const uint4*)(ap + 8);
            *(uint4*)&Ah[arow * LDSD + ahalf] = v0;
            *(uint4*)&Ah[arow * LDSD + ahalf + 8] = v1;
            const size_t bbase = (size_t)(bn + brow) * Kp + k0 + bq;
            uint4 w0 = *(const uint4*)(Bthg + bbase);
            uint4 w1 = *(const uint4*)(Btlg + bbase);
            *(uint4*)&Bh[brow * LDSD + bq] = w0;
            *(uint4*)&Bl[brow * LDSD + bq] = w1;
        }
        __syncthreads();
        bf16x8s afh[2], bfh[4], bfl[4];
#pragma unroll
        for (int mi = 0; mi < 2; ++mi) {
            int r = w * 32 + mi * 16 + lr;
            afh[mi] = *(const bf16x8s*)&Ah[r * LDSD + kgrp * 8];
        }
#pragma unroll
        for (int ni = 0; ni < 4; ++ni) {
            int r = ni * 16 + lr;
            bfh[ni] = *(const bf16x8s*)&Bh[r * LDSD + kgrp * 8];
            bfl[ni] = *(const bf16x8s*)&Bl[r * LDSD + kgrp * 8];
        }
#pragma unroll
        for (int mi = 0; mi < 2; ++mi)
#pragma unroll
            for (int ni = 0; ni < 4; ++ni) {
                acc[mi][ni] = __builtin_amdgcn_mfma_f32_16x16x32_bf16(afh[mi], bfh[ni], acc[mi][ni], 0, 0, 0);
                acc[mi][ni] = __builtin_amdgcn_mfma_f32_16x16x32_bf16(afh[mi], bfl[ni], acc[mi][ni], 0, 0, 0);
            }
        __syncthreads();
    }

#pragma unroll
    for (int mi = 0; mi < 2; ++mi) {
#pragma unroll
        for (int ni = 0; ni < 4; ++ni) {
            int col = bn + ni * 16 + lr;
            float bv = (col < N) ? bias[col] : 0.f;
            int row0 = bm + w * 32 + mi * 16 + kgrp * 4;
#pragma unroll
            for (int r = 0; r < 4; ++r) {
                float v = fmaxf(acc[mi][ni][r] + bv, 0.f); // relu
                int row = row0 + r;
                bool ok = (col < N) && (!MASK_ROW || row < M);
                if (ok) {
                    if (OUT_BF16) Cb[(size_t)row * ldc + col] = __float2bfloat16(v);
                    else Cf[(size_t)row * ldc + col] = v;
                }
            }
        }
    }
}

// ---------------- attention: fixed-max, log2-domain, DPP reduce, bf16 T out ----------------
__global__ __launch_bounds__(256) void attn_kernel(
    const float* __restrict__ R,        // [N_HE][216], scores pre-scaled by SL2E
    const float* __restrict__ q_t,      // [1489][64]
    const int2* __restrict__ rows2_all, // [3][N_HE] group-relative (start,end)
    const int* __restrict__ ebuf_all,   // [3][NBIN*BINCAP], holds d<<8 byte offsets
    bf16* __restrict__ T)               // [M_PAD][192] bf16
{
    int wid = blockIdx.x * 4 + (threadIdx.x >> 6);
    int lane = threadIdx.x & 63;
    int g = wid / N_HE;
    int h = wid - g * N_HE;
    const int toff_tab[3] = {0, 167, 1048};
    const char* qb = (const char*)(q_t + (size_t)toff_tab[g] * Q_DIM);
    const int* ebuf = ebuf_all + (size_t)g * NBIN * BINCAP;
    int2 se = rows2_all[g * N_HE + h];
    int start = se.x, end = se.y;

    int sub = lane >> 4, sl = lane & 15;
    const float* Rrow = R + (size_t)h * R_STRIDE + g * 72;
    float4 r4 = *reinterpret_cast<const float4*>(Rrow + sl * 4);
    float ch = Rrow[64];
    int slo = sl * 16;

    float denom = 0.f;
    float acc0 = 0.f, acc1 = 0.f, acc2 = 0.f, acc3 = 0.f;

    for (int i0 = start + sub * 2; i0 < end; i0 += 8) {
        bool ok1 = (i0 + 1) < end;
        int o0 = ebuf[i0];
        int o1 = ebuf[ok1 ? i0 + 1 : i0];
        float4 t0 = *reinterpret_cast<const float4*>(qb + o0 + slo);
        float4 t1 = *reinterpret_cast<const float4*>(qb + o1 + slo);
        float p0 = t0.x * r4.x;
        p0 = fmaf(t0.y, r4.y, p0); p0 = fmaf(t0.z, r4.z, p0); p0 = fmaf(t0.w, r4.w, p0);
        float p1 = t1.x * r4.x;
        p1 = fmaf(t1.y, r4.y, p1); p1 = fmaf(t1.z, r4.z, p1); p1 = fmaf(t1.w, r4.w, p1);
        p0 = red16(p0);
        p1 = red16(p1);
        float s0 = p0 + ch; s0 = fmaxf(s0, 0.01f * s0);   // leaky_relu (pre-scaled)
        float s1 = p1 + ch; s1 = fmaxf(s1, 0.01f * s1);
        float w0 = exp2_fast(s0);
        float w1 = ok1 ? exp2_fast(s1) : 0.f;
        denom += w0 + w1;
        acc0 = fmaf(w0, t0.x, fmaf(w1, t1.x, acc0));
        acc1 = fmaf(w0, t0.y, fmaf(w1, t1.y, acc1));
        acc2 = fmaf(w0, t0.z, fmaf(w1, t1.z, acc2));
        acc3 = fmaf(w0, t0.w, fmaf(w1, t1.w, acc3));
    }

    // cross-subgroup LANE-WISE sums (lane i <-> i^16, i^32): must be shfl, not row_bcast
    denom += __shfl_xor(denom, 16, 64); denom += __shfl_xor(denom, 32, 64);
    acc0 += __shfl_xor(acc0, 16, 64); acc0 += __shfl_xor(acc0, 32, 64);
    acc1 += __shfl_xor(acc1, 16, 64); acc1 += __shfl_xor(acc1, 32, 64);
    acc2 += __shfl_xor(acc2, 16, 64); acc2 += __shfl_xor(acc2, 32, 64);
    acc3 += __shfl_xor(acc3, 16, 64); acc3 += __shfl_xor(acc3, 32, 64);
    if (sub == 0) {
        float rden = 1.f / fmaxf(denom, 1e-20f);
        ushort4 o;
        o.x = bf16bits(acc0 * rden);
        o.y = bf16bits(acc1 * rden);
        o.z = bf16bits(acc2 * rden);
        o.w = bf16bits(acc3 * rden);
        *reinterpret_cast<ushort4*>(T + (size_t)h * T_STRIDE + g * 64 + sl * 4) = o;
    }
}

// ---------------- launch ----------------
extern "C" void kernel_launch(void* const* d_in, const int* in_sizes, int n_in,
                              void* d_out, int out_size, void* d_ws, size_t ws_size,
                              hipStream_t stream)
{
    const float* he_feat = (const float*)d_in[0];
    float* out = (float*)d_out;

    EdgeIdx Esrc, Edst;
    for (int g = 0; g < 3; ++g) {
        Esrc.p[g] = (const int*)d_in[34 + 2 * g];
        Edst.p[g] = (const int*)d_in[35 + 2 * g];
    }

    char* base = (char*)d_ws;
    size_t off = 0;
    auto alloc = [&](size_t bytes) -> void* {
        void* r = (void*)(base + off);
        off = (off + bytes + 255) & ~(size_t)255;
        return r;
    };
    // ---- persistent small region (~1.5 MB) ----
    bf16* WRt_hi = (bf16*)alloc(256 * KP_HE * 2);
    bf16* WRt_lo = (bf16*)alloc(256 * KP_HE * 2);
    float* bR = (float*)alloc(R_STRIDE * 4);
    bf16* Wct_hi = (bf16*)alloc(256 * T_STRIDE * 2);
    bf16* Wct_lo = (bf16*)alloc(256 * T_STRIDE * 2);
    float* b_comp = (float*)alloc(256 * 4);
    bf16* Wm2t_hi = (bf16*)alloc(128 * 256 * 2);
    bf16* Wm2t_lo = (bf16*)alloc(128 * 256 * 2);
    float* q_t = (float*)alloc(N_NODES * Q_DIM * 4);
    int* bincursor = (int*)alloc(3 * NBIN * 4);
    int2* rows2 = (int2*)alloc((size_t)3 * N_HE * 8);
    // ---- big buffers with lifetime overlays (~80 MB total) ----
    size_t T_start = off;
    bf16* T = (bf16*)alloc((size_t)M_PAD * T_STRIDE * 2);      // 19.2 MB [attn -> mlp1]
    size_t R_start = off;
    float* R = (float*)alloc((size_t)N_HE * R_STRIDE * 4);     // 43.2 MB [R-gemm -> attn]
    int* ebuf = (int*)alloc((size_t)3 * NBIN * BINCAP * 4);    // 15.4 MB [csr -> attn]
    // overlays:
    unsigned* binbuf = (unsigned*)(base + T_start);             // 15.4 MB [scatter -> csr], dead before attn writes T
    bf16* h1 = (bf16*)(base + R_start);                         // 25.6 MB [mlp1 -> mlp2], over dead R

    hipMemsetAsync(bincursor, 0, 3 * NBIN * 4, stream);

    // ---- fused scatter + prep ----
    PrepArgs P;
    P.w1w = (const float*)d_in[4]; P.w1b = (const float*)d_in[5];
    P.w2w = (const float*)d_in[6]; P.w2b = (const float*)d_in[7];
    for (int g = 0; g < 3; ++g) {
        P.w6[g] = (const float*)d_in[18 + 4 * g];
        P.b6[g] = (const float*)d_in[19 + 4 * g];
        P.w7[g] = (const float*)d_in[20 + 4 * g];
        P.b7[g] = (const float*)d_in[21 + 4 * g];
        P.feat[g] = (const float*)d_in[1 + g];
        P.w5[g] = (const float*)d_in[12 + 2 * g];
        P.b5[g] = (const float*)d_in[13 + 2 * g];
    }
    P.WRt_hi = WRt_hi; P.WRt_lo = WRt_lo; P.bR = bR;
    P.mlp1w = (const float*)d_in[30]; P.mlp1b = (const float*)d_in[31];
    P.Wct_hi = Wct_hi; P.Wct_lo = Wct_lo; P.b_comp = b_comp;
    P.mlp2w = (const float*)d_in[32];
    P.Wm2t_hi = Wm2t_hi; P.Wm2t_lo = Wm2t_lo;
    P.q_t = q_t;
    scatter_prep_fused_kernel<<<SCAT_BLKS + PREP_BLKS, 256, 0, stream>>>(
        Esrc, Edst, bincursor, binbuf, P);

    // ---- fused CSR finalize + R-gemm (independent dep chains) ----
    csr_gemm_fused_kernel<<<3 * NBIN + MB * 4, 256, 0, stream>>>(
        binbuf, bincursor, rows2, ebuf, he_feat, WRt_hi, WRt_lo, bR, R);

    // ---- attention -> T bf16 (overwrites binbuf: dead) ----
    attn_kernel<<<(3 * N_HE) / 4, 256, 0, stream>>>(R, q_t, rows2, ebuf, T);

    const float* mlp2b = (const float*)d_in[33];
    // h1 = relu(T @ W_comp + b_comp) -> bf16 [M_PAD][256]  (overwrites R: dead)
    mfma_gemm_bf16A_kernel<true, false><<<dim3(MB, 4), 256, 0, stream>>>(
        T, T_STRIDE, T_STRIDE, Wct_hi, Wct_lo, b_comp, nullptr, h1, M_PAD, 256, 256);
    // out = relu(h1 @ mlp2w + mlp2b) -> f32 [N_HE][128]
    mfma_gemm_bf16A_kernel<false, true><<<dim3(MB, 2), 256, 0, stream>>>(
        h1, 256, 256, Wm2t_hi, Wm2t_lo, mlp2b, out, nullptr, N_HE, E_DIM, E_DIM);
}